// Round 1
// baseline (5173.668 us; speedup 1.0000x reference)
//
#include <hip/hip_runtime.h>
#include <hip/hip_bf16.h>

#define HD  256
#define HD2 512
#define HD3 768
#define HD4 1024
#define NB  4096   // number of graphs (B)

static __device__ __forceinline__ float lrelu(float x) { return x >= 0.f ? x : 0.01f * x; }
// order-preserving float<->uint encoding for atomicMax on floats
static __device__ __forceinline__ unsigned fenc(float f) {
  unsigned u = __float_as_uint(f);
  return (u & 0x80000000u) ? ~u : (u | 0x80000000u);
}
static __device__ __forceinline__ float fdec(unsigned e) {
  unsigned b = (e & 0x80000000u) ? (e & 0x7fffffffu) : ~e;
  return __uint_as_float(b);
}

// ---------------- generic fp32 GEMM: C[M,Nout] (+)= Ahat[M,K] @ W[Nout,K]^T ---
// Ahat row r = A[gather[r]] (optional) with optional per-k affine (BN fused).
#define TS 64
#define KS 16
__global__ __launch_bounds__(256)
void gemm_tn(const float* __restrict__ A, int lda,
             const int* __restrict__ gather,
             const float* __restrict__ ascale, const float* __restrict__ ashift,
             const float* __restrict__ W, int ldw,
             float* __restrict__ C, int ldc,
             int M, int K, int accumulate)
{
  __shared__ float As[KS][TS + 1];
  __shared__ float Ws[KS][TS + 1];
  const int tid = threadIdx.x;
  const int bm = blockIdx.x * TS;
  const int bn = blockIdx.y * TS;
  const int r  = tid >> 2;          // 0..63 tile row to load
  const int kc = (tid & 3) << 2;    // k sub-column (float4)
  const int tm = (tid >> 4) << 2;   // 4x4 micro-tile coords
  const int tn = (tid & 15) << 2;
  float acc[4][4] = {};
  for (int k0 = 0; k0 < K; k0 += KS) {
    float4 av = make_float4(0.f, 0.f, 0.f, 0.f);
    const int row = bm + r;
    if (row < M) {
      const int arow = gather ? gather[row] : row;
      av = *(const float4*)(A + (size_t)arow * lda + k0 + kc);
    }
    if (ascale) {
      av.x = fmaf(av.x, ascale[k0 + kc + 0], ashift[k0 + kc + 0]);
      av.y = fmaf(av.y, ascale[k0 + kc + 1], ashift[k0 + kc + 1]);
      av.z = fmaf(av.z, ascale[k0 + kc + 2], ashift[k0 + kc + 2]);
      av.w = fmaf(av.w, ascale[k0 + kc + 3], ashift[k0 + kc + 3]);
    }
    As[kc + 0][r] = av.x; As[kc + 1][r] = av.y; As[kc + 2][r] = av.z; As[kc + 3][r] = av.w;
    float4 wv = *(const float4*)(W + (size_t)(bn + r) * ldw + k0 + kc);
    Ws[kc + 0][r] = wv.x; Ws[kc + 1][r] = wv.y; Ws[kc + 2][r] = wv.z; Ws[kc + 3][r] = wv.w;
    __syncthreads();
    #pragma unroll
    for (int kk = 0; kk < KS; ++kk) {
      float a_[4], b_[4];
      #pragma unroll
      for (int i = 0; i < 4; ++i) a_[i] = As[kk][tm + i];
      #pragma unroll
      for (int j = 0; j < 4; ++j) b_[j] = Ws[kk][tn + j];
      #pragma unroll
      for (int i = 0; i < 4; ++i)
        #pragma unroll
        for (int j = 0; j < 4; ++j) acc[i][j] = fmaf(a_[i], b_[j], acc[i][j]);
    }
    __syncthreads();
  }
  #pragma unroll
  for (int i = 0; i < 4; ++i) {
    const int row = bm + tm + i;
    if (row < M) {
      float4* cp = (float4*)(C + (size_t)row * ldc + bn + tn);
      float4 v = make_float4(acc[i][0], acc[i][1], acc[i][2], acc[i][3]);
      if (accumulate) {
        float4 o = *cp;
        v.x += o.x; v.y += o.y; v.z += o.z; v.w += o.w;
      }
      *cp = v;
    }
  }
}

// per-vocab attention scalars: psv[l][v] = zemb[v, l*H:(l+1)*H] . a_s[l]
__global__ __launch_bounds__(256)
void psv_kernel(const float* __restrict__ zemb, const float* __restrict__ as_,
                const float* __restrict__ ad_, float* __restrict__ psv,
                float* __restrict__ pdv, int V)
{
  int v = (int)((blockIdx.x * 256u + threadIdx.x) >> 6);
  int l = blockIdx.y;
  int lane = threadIdx.x & 63;
  if (v >= V) return;
  float4 zv = ((const float4*)(zemb + (size_t)v * HD4 + (size_t)l * HD))[lane];
  float4 a  = ((const float4*)(as_ + (size_t)l * HD))[lane];
  float4 b  = ((const float4*)(ad_ + (size_t)l * HD))[lane];
  float s = zv.x * a.x + zv.y * a.y + zv.z * a.z + zv.w * a.w;
  float d = zv.x * b.x + zv.y * b.y + zv.z * b.z + zv.w * b.w;
  #pragma unroll
  for (int o = 32; o; o >>= 1) { s += __shfl_down(s, o); d += __shfl_down(d, o); }
  if (lane == 0) { psv[(size_t)l * V + v] = s; pdv[(size_t)l * V + v] = d; }
}

__global__ void init_newh(float* __restrict__ out, const float* __restrict__ bout, size_t total) {
  size_t i = (size_t)blockIdx.x * 256 + threadIdx.x;
  size_t st = (size_t)gridDim.x * 256;
  for (; i < total; i += st) out[i] = bout[i & (HD - 1)];
}

__global__ void cnt_kernel(const int* __restrict__ n2g, float* __restrict__ cnt, int N) {
  int n = blockIdx.x * 256 + threadIdx.x;
  if (n < N) unsafeAtomicAdd(&cnt[n2g[n]], 1.f);
}

// acc[n2g[n]] += X[gather? gather[n] : n]   (one block per node, thread = channel)
__global__ __launch_bounds__(256)
void seg_accum(const float* __restrict__ X, const int* __restrict__ gather,
               const int* __restrict__ n2g, float* __restrict__ acc, int N)
{
  int n = blockIdx.x;
  if (n >= N) return;
  int h = threadIdx.x;
  int row = gather ? gather[n] : n;
  unsafeAtomicAdd(&acc[(size_t)n2g[n] * HD + h], X[(size_t)row * HD + h]);
}

__global__ void mean_div(float* __restrict__ acc, const float* __restrict__ cnt, int total) {
  int i = blockIdx.x * 256 + threadIdx.x;
  if (i < total) acc[i] /= fmaxf(cnt[i >> 8], 1.f);
}

__global__ void edge_max(const int* __restrict__ src, const int* __restrict__ dst,
                         const int* __restrict__ wid, const float* __restrict__ psv,
                         const float* __restrict__ pdv, unsigned* __restrict__ mkey, int E)
{
  int e = blockIdx.x * 256 + threadIdx.x;
  if (e >= E) return;
  int d = dst[e];
  float sc = lrelu(psv[wid[src[e]]] + pdv[wid[d]]);
  atomicMax(&mkey[d], fenc(sc));
}

__global__ void edge_sum(const int* __restrict__ src, const int* __restrict__ dst,
                         const int* __restrict__ wid, const float* __restrict__ psv,
                         const float* __restrict__ pdv, const unsigned* __restrict__ mkey,
                         float* __restrict__ ssum, float* __restrict__ exb, int E)
{
  int e = blockIdx.x * 256 + threadIdx.x;
  if (e >= E) return;
  int d = dst[e];
  float sc = lrelu(psv[wid[src[e]]] + pdv[wid[d]]);
  unsigned k = mkey[d];
  float m = (k == 0u) ? 0.f : fdec(k);   // k==0: segment had no edges (unreachable here)
  float ex = expf(sc - m);
  exb[e] = ex;
  unsafeAtomicAdd(&ssum[d], ex);
}

// hr[dst[e]] += alpha_e * zemb_l[wid[src[e]]]  -- one wave (64 lanes x float4) per edge
__global__ __launch_bounds__(256)
void edge_agg(const int* __restrict__ src, const int* __restrict__ dst,
              const int* __restrict__ wid, const float* __restrict__ exb,
              const float* __restrict__ ssum, const float* __restrict__ zl,
              float* __restrict__ hr, int E)
{
  int w = (int)((blockIdx.x * 256u + threadIdx.x) >> 6);
  int lane = threadIdx.x & 63;
  if (w >= E) return;
  int s = src[w], d = dst[w];
  float sv = ssum[d];
  float al = exb[w] / (sv == 0.f ? 1.f : sv);
  float4 zv = ((const float4*)(zl + (size_t)wid[s] * HD4))[lane];
  float* hp = hr + (size_t)d * HD + (lane << 2);
  unsafeAtomicAdd(hp + 0, al * zv.x);
  unsafeAtomicAdd(hp + 1, al * zv.y);
  unsafeAtomicAdd(hp + 2, al * zv.z);
  unsafeAtomicAdd(hp + 3, al * zv.w);
}

// in-place relu + per-channel sum/sumsq partials (thread t owns channel t)
__global__ __launch_bounds__(256)
void bn_stats(float* __restrict__ hr, float* __restrict__ bs, float* __restrict__ bq, int N)
{
  int h = threadIdx.x;
  int r0 = blockIdx.x * 256;
  int r1 = min(r0 + 256, N);
  float s = 0.f, q = 0.f;
  for (int r = r0; r < r1; ++r) {
    float v = fmaxf(hr[(size_t)r * HD + h], 0.f);
    hr[(size_t)r * HD + h] = v;
    s += v; q = fmaf(v, v, q);
  }
  unsafeAtomicAdd(&bs[h], s);
  unsafeAtomicAdd(&bq[h], q);
}

__global__ void bn_fin(const float* __restrict__ bs, const float* __restrict__ bq,
                       const float* __restrict__ gamma, const float* __restrict__ beta,
                       float* __restrict__ sc, float* __restrict__ sh, float invN)
{
  int h = threadIdx.x;
  float mu  = bs[h] * invN;
  float var = fmaxf(bq[h] * invN - mu * mu, 0.f);
  float s = gamma[h] * rsqrtf(var + 1e-5f);
  sc[h] = s;
  sh[h] = fmaf(-mu, s, beta[h]);
}

// torch GRU cell; gh==null means hprev==0 (gh = bhh only)
__global__ __launch_bounds__(256)
void gru_cell(const float* __restrict__ gi, const float* __restrict__ gh,
              const float* __restrict__ bih, const float* __restrict__ bhh,
              const float* __restrict__ hprev, int hld,
              float* __restrict__ out, int outld, int Bn)
{
  int i = blockIdx.x * 256 + threadIdx.x;
  if (i >= Bn * HD) return;
  int b = i >> 8, h = i & 255;
  const float* gr = gi + (size_t)b * HD3;
  float ir  = gr[h]       + bih[h];
  float iz  = gr[HD + h]  + bih[HD + h];
  float in_ = gr[HD2 + h] + bih[HD2 + h];
  float hrv = bhh[h], hzv = bhh[HD + h], hnv = bhh[HD2 + h];
  if (gh) {
    const float* gg = gh + (size_t)b * HD3;
    hrv += gg[h]; hzv += gg[HD + h]; hnv += gg[HD2 + h];
  }
  float hp = hprev ? hprev[(size_t)b * hld + h] : 0.f;
  float rg = 1.f / (1.f + expf(-(ir + hrv)));
  float zg = 1.f / (1.f + expf(-(iz + hzv)));
  float n  = tanhf(fmaf(rg, hnv, in_));
  out[(size_t)b * outld + h] = (1.f - zg) * n + zg * hp;
}

// h_readout = hf0 (y0[:,1,0:H]) + hb0 (y0[:,0,H:2H]) + hf1 + hb1
__global__ void readout_k(const float* __restrict__ y0, const float* __restrict__ hf1,
                          const float* __restrict__ hf2, float* __restrict__ out, int Bn)
{
  int i = blockIdx.x * 256 + threadIdx.x;
  if (i >= Bn * HD) return;
  int b = i >> 8, h = i & 255;
  out[i] = y0[(size_t)b * HD4 + HD2 + h] + y0[(size_t)b * HD4 + HD + h] + hf1[i] + hf2[i];
}

extern "C" void kernel_launch(void* const* d_in, const int* in_sizes, int n_in,
                              void* d_out, int out_size, void* d_ws, size_t ws_size,
                              hipStream_t stream)
{
  const int*   wid   = (const int*)d_in[0];
  const int*   src   = (const int*)d_in[1];
  const int*   dst   = (const int*)d_in[2];
  const int*   n2g   = (const int*)d_in[3];
  const float* emb   = (const float*)d_in[4];
  const float* gatW  = (const float*)d_in[5];
  const float* gatAs = (const float*)d_in[6];
  const float* gatAd = (const float*)d_in[7];
  const float* gatG  = (const float*)d_in[8];
  const float* gatB  = (const float*)d_in[9];
  const float* Wout  = (const float*)d_in[10];
  const float* bout  = (const float*)d_in[11];
  const float* Wih0  = (const float*)d_in[12];
  const float* Whh0  = (const float*)d_in[13];
  const float* bih0  = (const float*)d_in[14];
  const float* bhh0  = (const float*)d_in[15];
  const float* Wih1  = (const float*)d_in[16];
  const float* Whh1  = (const float*)d_in[17];
  const float* bih1  = (const float*)d_in[18];
  const float* bhh1  = (const float*)d_in[19];
  (void)n_in; (void)out_size; (void)ws_size;

  const int N = in_sizes[0];
  const int E = in_sizes[1];
  const int V = in_sizes[4] / HD;

  float* out_newh = (float*)d_out;             // [N,H]
  float* out_read = out_newh + (size_t)N * HD; // [B,H]

  // ---- workspace carve-up (all fp32; every float4-accessed buffer 16B aligned)
  float* p = (float*)d_ws;
  float* hr    = p; p += (size_t)N * HD;       // per-layer aggregated features
  float* zemb  = p; p += (size_t)V * HD4;      // emb @ [4 layers W]^T
  float* psv   = p; p += 4 * (size_t)V;
  float* pdv   = p; p += 4 * (size_t)V;
  float* ssum  = p; p += N;                    // ssum+mkey contiguous (one memset)
  unsigned* mkey = (unsigned*)p; p += N;
  float* exb   = p; p += E;
  float* cnt   = p; p += NB;                   // cnt+mean1+mean2 contiguous
  float* mean1 = p; p += (size_t)NB * HD;
  float* mean2 = p; p += (size_t)NB * HD;
  float* gi    = p; p += (size_t)NB * HD3;
  float* gh    = p; p += (size_t)NB * HD3;
  float* y0    = p; p += (size_t)NB * HD4;     // [B,2,2H] layer-0 outputs
  float* htA   = p; p += (size_t)NB * HD;
  float* hf1   = p; p += (size_t)NB * HD;
  float* hf2   = p; p += (size_t)NB * HD;
  float* bnsum = p; p += HD;                   // bnsum+bnsq contiguous
  float* bnsq  = p; p += HD;
  float* bnsc  = p; p += HD;
  float* bnsh  = p; p += HD;

  auto gemm = [&](const float* A, int lda, const int* gath, const float* asc, const float* ash,
                  const float* W, int ldw, float* C, int ldc, int M, int Nout, int K, int accum) {
    dim3 g((unsigned)((M + TS - 1) / TS), (unsigned)(Nout / TS));
    gemm_tn<<<g, 256, 0, stream>>>(A, lda, gath, asc, ash, W, ldw, C, ldc, M, K, accum);
  };
  auto cell = [&](const float* gi_, const float* gh_, const float* bi, const float* bh,
                  const float* hp, int hld, float* op, int ol) {
    gru_cell<<<(NB * HD + 255) / 256, 256, 0, stream>>>(gi_, gh_, bi, bh, hp, hld, op, ol, NB);
  };

  // zemb[v, i*H+h] = sum_k emb[v,k] * gat_W[i,h,k]   (gat_W viewed as [4H, H])
  gemm(emb, HD, nullptr, nullptr, nullptr, gatW, HD, zemb, HD4, V, HD4, HD, 0);
  psv_kernel<<<dim3((V + 3) / 4, 4), 256, 0, stream>>>(zemb, gatAs, gatAd, psv, pdv, V);

  init_newh<<<4096, 256, 0, stream>>>(out_newh, bout, (size_t)N * HD);

  hipMemsetAsync(cnt, 0, (size_t)(NB + 2 * NB * HD) * sizeof(float), stream);
  cnt_kernel<<<(N + 255) / 256, 256, 0, stream>>>(n2g, cnt, N);
  seg_accum<<<N, 256, 0, stream>>>(emb, wid, n2g, mean1, N);
  mean_div<<<(NB * HD + 255) / 256, 256, 0, stream>>>(mean1, cnt, NB * HD);

  for (int l = 0; l < 4; ++l) {
    const float* psv_l = psv + (size_t)l * V;
    const float* pdv_l = pdv + (size_t)l * V;
    hipMemsetAsync(ssum, 0, (size_t)2 * N * sizeof(float), stream);   // ssum + mkey
    edge_max<<<(E + 255) / 256, 256, 0, stream>>>(src, dst, wid, psv_l, pdv_l, mkey, E);
    edge_sum<<<(E + 255) / 256, 256, 0, stream>>>(src, dst, wid, psv_l, pdv_l, mkey, ssum, exb, E);
    hipMemsetAsync(hr, 0, (size_t)N * HD * sizeof(float), stream);
    edge_agg<<<(E + 3) / 4, 256, 0, stream>>>(src, dst, wid, exb, ssum,
                                              zemb + (size_t)l * HD, hr, E);
    hipMemsetAsync(bnsum, 0, 2 * HD * sizeof(float), stream);
    bn_stats<<<(N + 255) / 256, 256, 0, stream>>>(hr, bnsum, bnsq, N);
    bn_fin<<<1, HD, 0, stream>>>(bnsum, bnsq, gatG + l * HD, gatB + l * HD, bnsc, bnsh, 1.f / (float)N);
    // new_h += BN(hr) @ W_out[:, l*H:(l+1)*H]^T  (BN fused into A-load)
    gemm(hr, HD, nullptr, bnsc, bnsh, Wout + l * HD, HD4, out_newh, HD, N, HD, HD, 1);
  }

  seg_accum<<<N, 256, 0, stream>>>(out_newh, nullptr, n2g, mean2, N);
  mean_div<<<(NB * HD + 255) / 256, 256, 0, stream>>>(mean2, cnt, NB * HD);

  // ---- GRU (T=2, 2 layers, bidirectional). y0[b,t,c]: c = t*2H + dir*H + h
  // layer0 forward
  gemm(mean1, HD, nullptr, nullptr, nullptr, Wih0, HD, gi, HD3, NB, HD3, HD, 0);
  cell(gi, nullptr, bih0, bhh0, nullptr, 0, y0 + 0, HD4);
  gemm(mean2, HD, nullptr, nullptr, nullptr, Wih0, HD, gi, HD3, NB, HD3, HD, 0);
  gemm(y0 + 0, HD4, nullptr, nullptr, nullptr, Whh0, HD, gh, HD3, NB, HD3, HD, 0);
  cell(gi, gh, bih0, bhh0, y0 + 0, HD4, y0 + HD2, HD4);
  // layer0 backward
  const float* Wih0b = Wih0 + (size_t)HD3 * HD;
  const float* Whh0b = Whh0 + (size_t)HD3 * HD;
  gemm(mean2, HD, nullptr, nullptr, nullptr, Wih0b, HD, gi, HD3, NB, HD3, HD, 0);
  cell(gi, nullptr, bih0 + HD3, bhh0 + HD3, nullptr, 0, y0 + HD2 + HD, HD4);
  gemm(mean1, HD, nullptr, nullptr, nullptr, Wih0b, HD, gi, HD3, NB, HD3, HD, 0);
  gemm(y0 + HD2 + HD, HD4, nullptr, nullptr, nullptr, Whh0b, HD, gh, HD3, NB, HD3, HD, 0);
  cell(gi, gh, bih0 + HD3, bhh0 + HD3, y0 + HD2 + HD, HD4, y0 + HD, HD4);
  // layer1 forward (input = y0[:,t,:] of width 2H)
  gemm(y0 + 0, HD4, nullptr, nullptr, nullptr, Wih1, HD2, gi, HD3, NB, HD3, HD2, 0);
  cell(gi, nullptr, bih1, bhh1, nullptr, 0, htA, HD);
  gemm(y0 + HD2, HD4, nullptr, nullptr, nullptr, Wih1, HD2, gi, HD3, NB, HD3, HD2, 0);
  gemm(htA, HD, nullptr, nullptr, nullptr, Whh1, HD, gh, HD3, NB, HD3, HD, 0);
  cell(gi, gh, bih1, bhh1, htA, HD, hf1, HD);
  // layer1 backward
  const float* Wih1b = Wih1 + (size_t)HD3 * HD2;
  const float* Whh1b = Whh1 + (size_t)HD3 * HD;
  gemm(y0 + HD2, HD4, nullptr, nullptr, nullptr, Wih1b, HD2, gi, HD3, NB, HD3, HD2, 0);
  cell(gi, nullptr, bih1 + HD3, bhh1 + HD3, nullptr, 0, htA, HD);
  gemm(y0 + 0, HD4, nullptr, nullptr, nullptr, Wih1b, HD2, gi, HD3, NB, HD3, HD2, 0);
  gemm(htA, HD, nullptr, nullptr, nullptr, Whh1b, HD, gh, HD3, NB, HD3, HD, 0);
  cell(gi, gh, bih1 + HD3, bhh1 + HD3, htA, HD, hf2, HD);

  readout_k<<<(NB * HD + 255) / 256, 256, 0, stream>>>(y0, hf1, hf2, out_read, NB);
}

// Round 2
// 2713.941 us; speedup vs baseline: 1.9063x; 1.9063x over previous
//
#include <hip/hip_runtime.h>
#include <hip/hip_bf16.h>

#define HD  256
#define HD2 512
#define HD3 768
#define HD4 1024
#define NB  4096   // number of graphs (B)

static __device__ __forceinline__ float lrelu(float x) { return x >= 0.f ? x : 0.01f * x; }

// ---------------- generic fp32 GEMM: C[M,Nout] (+)= Ahat[M,K] @ W[Nout,K]^T ---
// Ahat row r = A[r] with optional per-k affine (BN fused).
#define TS 64
#define KS 16
__global__ __launch_bounds__(256)
void gemm_tn(const float* __restrict__ A, int lda,
             const float* __restrict__ ascale, const float* __restrict__ ashift,
             const float* __restrict__ W, int ldw,
             float* __restrict__ C, int ldc,
             int M, int K, int accumulate)
{
  __shared__ float As[KS][TS + 1];
  __shared__ float Ws[KS][TS + 1];
  const int tid = threadIdx.x;
  const int bm = blockIdx.x * TS;
  const int bn = blockIdx.y * TS;
  const int r  = tid >> 2;          // 0..63 tile row to load
  const int kc = (tid & 3) << 2;    // k sub-column (float4)
  const int tm = (tid >> 4) << 2;   // 4x4 micro-tile coords
  const int tn = (tid & 15) << 2;
  float acc[4][4] = {};
  for (int k0 = 0; k0 < K; k0 += KS) {
    float4 av = make_float4(0.f, 0.f, 0.f, 0.f);
    const int row = bm + r;
    if (row < M) av = *(const float4*)(A + (size_t)row * lda + k0 + kc);
    if (ascale) {
      av.x = fmaf(av.x, ascale[k0 + kc + 0], ashift[k0 + kc + 0]);
      av.y = fmaf(av.y, ascale[k0 + kc + 1], ashift[k0 + kc + 1]);
      av.z = fmaf(av.z, ascale[k0 + kc + 2], ashift[k0 + kc + 2]);
      av.w = fmaf(av.w, ascale[k0 + kc + 3], ashift[k0 + kc + 3]);
    }
    As[kc + 0][r] = av.x; As[kc + 1][r] = av.y; As[kc + 2][r] = av.z; As[kc + 3][r] = av.w;
    float4 wv = *(const float4*)(W + (size_t)(bn + r) * ldw + k0 + kc);
    Ws[kc + 0][r] = wv.x; Ws[kc + 1][r] = wv.y; Ws[kc + 2][r] = wv.z; Ws[kc + 3][r] = wv.w;
    __syncthreads();
    #pragma unroll
    for (int kk = 0; kk < KS; ++kk) {
      float a_[4], b_[4];
      #pragma unroll
      for (int i = 0; i < 4; ++i) a_[i] = As[kk][tm + i];
      #pragma unroll
      for (int j = 0; j < 4; ++j) b_[j] = Ws[kk][tn + j];
      #pragma unroll
      for (int i = 0; i < 4; ++i)
        #pragma unroll
        for (int j = 0; j < 4; ++j) acc[i][j] = fmaf(a_[i], b_[j], acc[i][j]);
    }
    __syncthreads();
  }
  #pragma unroll
  for (int i = 0; i < 4; ++i) {
    const int row = bm + tm + i;
    if (row < M) {
      float4* cp = (float4*)(C + (size_t)row * ldc + bn + tn);
      float4 v = make_float4(acc[i][0], acc[i][1], acc[i][2], acc[i][3]);
      if (accumulate) {
        float4 o = *cp;
        v.x += o.x; v.y += o.y; v.z += o.z; v.w += o.w;
      }
      *cp = v;
    }
  }
}

// per-vocab attention scalars: psv[l][v] = zemb[v, l*H:(l+1)*H] . a_s[l]
__global__ __launch_bounds__(256)
void psv_kernel(const float* __restrict__ zemb, const float* __restrict__ as_,
                const float* __restrict__ ad_, float* __restrict__ psv,
                float* __restrict__ pdv, int V)
{
  int v = (int)((blockIdx.x * 256u + threadIdx.x) >> 6);
  int l = blockIdx.y;
  int lane = threadIdx.x & 63;
  if (v >= V) return;
  float4 zv = ((const float4*)(zemb + (size_t)v * HD4 + (size_t)l * HD))[lane];
  float4 a  = ((const float4*)(as_ + (size_t)l * HD))[lane];
  float4 b  = ((const float4*)(ad_ + (size_t)l * HD))[lane];
  float s = zv.x * a.x + zv.y * a.y + zv.z * a.z + zv.w * a.w;
  float d = zv.x * b.x + zv.y * b.y + zv.z * b.z + zv.w * b.w;
  #pragma unroll
  for (int o = 32; o; o >>= 1) { s += __shfl_down(s, o); d += __shfl_down(d, o); }
  if (lane == 0) { psv[(size_t)l * V + v] = s; pdv[(size_t)l * V + v] = d; }
}

__global__ void init_newh(float* __restrict__ out, const float* __restrict__ bout, size_t total) {
  size_t i = (size_t)blockIdx.x * 256 + threadIdx.x;
  size_t st = (size_t)gridDim.x * 256;
  for (; i < total; i += st) out[i] = bout[i & (HD - 1)];
}

__global__ void cnt_kernel(const int* __restrict__ n2g, float* __restrict__ cnt, int N) {
  int n = blockIdx.x * 256 + threadIdx.x;
  if (n < N) unsafeAtomicAdd(&cnt[n2g[n]], 1.f);
}

// acc[n2g[n]] += X[gather? gather[n] : n]   (one block per node, thread = channel)
__global__ __launch_bounds__(256)
void seg_accum(const float* __restrict__ X, const int* __restrict__ gather,
               const int* __restrict__ n2g, float* __restrict__ acc, int N)
{
  int n = blockIdx.x;
  if (n >= N) return;
  int h = threadIdx.x;
  int row = gather ? gather[n] : n;
  unsafeAtomicAdd(&acc[(size_t)n2g[n] * HD + h], X[(size_t)row * HD + h]);
}

__global__ void mean_div(float* __restrict__ acc, const float* __restrict__ cnt, int total) {
  int i = blockIdx.x * 256 + threadIdx.x;
  if (i < total) acc[i] /= fmaxf(cnt[i >> 8], 1.f);
}

// ---------------- CSR build (by dst) ----------------
__global__ void deg_hist(const int* __restrict__ dst, int* __restrict__ deg, int E) {
  int e = blockIdx.x * 256 + threadIdx.x;
  if (e < E) atomicAdd(&deg[dst[e]], 1);
}

#define SCB 1024  // elements per scan block
__global__ void scan_bsum(const int* __restrict__ deg, int* __restrict__ bsum, int N) {
  __shared__ int sh[256];
  int base = blockIdx.x * SCB;
  int t = threadIdx.x;
  int s = 0;
  for (int i = t; i < SCB; i += 256) { int idx = base + i; s += (idx < N) ? deg[idx] : 0; }
  sh[t] = s; __syncthreads();
  for (int o = 128; o; o >>= 1) { if (t < o) sh[t] += sh[t + o]; __syncthreads(); }
  if (t == 0) bsum[blockIdx.x] = sh[0];
}
__global__ void scan_small(int* __restrict__ bsum, int nb) {
  if (threadIdx.x == 0) {
    int acc = 0;
    for (int i = 0; i < nb; ++i) { int v = bsum[i]; bsum[i] = acc; acc += v; }
  }
}
__global__ void scan_final(const int* __restrict__ deg, const int* __restrict__ bsum,
                           int* __restrict__ rowptr, int N, int E) {
  __shared__ int sh[256];
  int base = blockIdx.x * SCB;
  int t = threadIdx.x;
  int idx0 = base + t * 4;
  int v[4]; int s = 0;
  #pragma unroll
  for (int j = 0; j < 4; ++j) { int idx = idx0 + j; v[j] = (idx < N) ? deg[idx] : 0; s += v[j]; }
  sh[t] = s; __syncthreads();
  for (int o = 1; o < 256; o <<= 1) {
    int x = (t >= o) ? sh[t - o] : 0;
    __syncthreads();
    sh[t] += x;
    __syncthreads();
  }
  int off = bsum[blockIdx.x] + ((t == 0) ? 0 : sh[t - 1]);
  #pragma unroll
  for (int j = 0; j < 4; ++j) {
    int idx = idx0 + j;
    if (idx < N) rowptr[idx] = off;
    off += v[j];
  }
  if (idx0 <= N - 1 && N - 1 < idx0 + 4) rowptr[N] = E;  // thread owning last element also writes end
}
__global__ void scatter_edges(const int* __restrict__ src, const int* __restrict__ dst,
                              const int* __restrict__ wid, int* __restrict__ cursor,
                              int* __restrict__ swids, int E) {
  int e = blockIdx.x * 256 + threadIdx.x;
  if (e >= E) return;
  int pos = atomicAdd(&cursor[dst[e]], 1);
  swids[pos] = wid[src[e]];
}

// ---------------- fused per-layer GAT: softmax + aggregate + relu + BN partials
// wave per node; lane owns 4 channels. zl = zemb + l*HD (row stride HD4).
__global__ __launch_bounds__(256)
void gat_node(const int* __restrict__ rowptr, const int* __restrict__ swids,
              const int* __restrict__ wid, const float* __restrict__ psv_l,
              const float* __restrict__ pdv_l, const float* __restrict__ zl,
              float* __restrict__ hr, float* __restrict__ bs, float* __restrict__ bq,
              int N)
{
  const int lane = threadIdx.x & 63;
  const int wv   = threadIdx.x >> 6;
  const int gw   = blockIdx.x * 4 + wv;
  const int nw   = gridDim.x * 4;
  float sreg[4] = {}, qreg[4] = {};
  for (int n = gw; n < N; n += nw) {
    const int b0 = rowptr[n], b1 = rowptr[n + 1];
    const float pdn = pdv_l[wid[n]];
    float m = -INFINITY;
    for (int i = b0; i < b1; ++i) m = fmaxf(m, lrelu(psv_l[swids[i]] + pdn));
    if (b0 == b1) m = 0.f;
    float s = 0.f;
    float4 acc = make_float4(0.f, 0.f, 0.f, 0.f);
    for (int i = b0; i < b1; ++i) {
      const int sw = swids[i];
      const float ex = expf(lrelu(psv_l[sw] + pdn) - m);
      s += ex;
      float4 zv = ((const float4*)(zl + (size_t)sw * HD4))[lane];
      acc.x = fmaf(ex, zv.x, acc.x);
      acc.y = fmaf(ex, zv.y, acc.y);
      acc.z = fmaf(ex, zv.z, acc.z);
      acc.w = fmaf(ex, zv.w, acc.w);
    }
    const float inv = 1.f / (s == 0.f ? 1.f : s);
    float4 v;
    v.x = fmaxf(acc.x * inv, 0.f);
    v.y = fmaxf(acc.y * inv, 0.f);
    v.z = fmaxf(acc.z * inv, 0.f);
    v.w = fmaxf(acc.w * inv, 0.f);
    ((float4*)(hr + (size_t)n * HD))[lane] = v;
    sreg[0] += v.x; sreg[1] += v.y; sreg[2] += v.z; sreg[3] += v.w;
    qreg[0] = fmaf(v.x, v.x, qreg[0]); qreg[1] = fmaf(v.y, v.y, qreg[1]);
    qreg[2] = fmaf(v.z, v.z, qreg[2]); qreg[3] = fmaf(v.w, v.w, qreg[3]);
  }
  __shared__ float ls[4][64][4];
  __shared__ float lq[4][64][4];
  #pragma unroll
  for (int j = 0; j < 4; ++j) { ls[wv][lane][j] = sreg[j]; lq[wv][lane][j] = qreg[j]; }
  __syncthreads();
  if (wv == 0) {
    #pragma unroll
    for (int j = 0; j < 4; ++j) {
      float s4 = ls[0][lane][j] + ls[1][lane][j] + ls[2][lane][j] + ls[3][lane][j];
      float q4 = lq[0][lane][j] + lq[1][lane][j] + lq[2][lane][j] + lq[3][lane][j];
      unsafeAtomicAdd(&bs[lane * 4 + j], s4);
      unsafeAtomicAdd(&bq[lane * 4 + j], q4);
    }
  }
}

__global__ void bn_fin(const float* __restrict__ bs, const float* __restrict__ bq,
                       const float* __restrict__ gamma, const float* __restrict__ beta,
                       float* __restrict__ sc, float* __restrict__ sh, float invN)
{
  int h = threadIdx.x;
  float mu  = bs[h] * invN;
  float var = fmaxf(bq[h] * invN - mu * mu, 0.f);
  float s = gamma[h] * rsqrtf(var + 1e-5f);
  sc[h] = s;
  sh[h] = fmaf(-mu, s, beta[h]);
}

// torch GRU cell; gh==null means hprev==0 (gh = bhh only)
__global__ __launch_bounds__(256)
void gru_cell(const float* __restrict__ gi, const float* __restrict__ gh,
              const float* __restrict__ bih, const float* __restrict__ bhh,
              const float* __restrict__ hprev, int hld,
              float* __restrict__ out, int outld, int Bn)
{
  int i = blockIdx.x * 256 + threadIdx.x;
  if (i >= Bn * HD) return;
  int b = i >> 8, h = i & 255;
  const float* gr = gi + (size_t)b * HD3;
  float ir  = gr[h]       + bih[h];
  float iz  = gr[HD + h]  + bih[HD + h];
  float in_ = gr[HD2 + h] + bih[HD2 + h];
  float hrv = bhh[h], hzv = bhh[HD + h], hnv = bhh[HD2 + h];
  if (gh) {
    const float* gg = gh + (size_t)b * HD3;
    hrv += gg[h]; hzv += gg[HD + h]; hnv += gg[HD2 + h];
  }
  float hp = hprev ? hprev[(size_t)b * hld + h] : 0.f;
  float rg = 1.f / (1.f + expf(-(ir + hrv)));
  float zg = 1.f / (1.f + expf(-(iz + hzv)));
  float n  = tanhf(fmaf(rg, hnv, in_));
  out[(size_t)b * outld + h] = (1.f - zg) * n + zg * hp;
}

// h_readout = hf0 (y0[:,1,0:H]) + hb0 (y0[:,0,H:2H]) + hf1 + hb1
__global__ void readout_k(const float* __restrict__ y0, const float* __restrict__ hf1,
                          const float* __restrict__ hf2, float* __restrict__ out, int Bn)
{
  int i = blockIdx.x * 256 + threadIdx.x;
  if (i >= Bn * HD) return;
  int b = i >> 8, h = i & 255;
  out[i] = y0[(size_t)b * HD4 + HD2 + h] + y0[(size_t)b * HD4 + HD + h] + hf1[i] + hf2[i];
}

extern "C" void kernel_launch(void* const* d_in, const int* in_sizes, int n_in,
                              void* d_out, int out_size, void* d_ws, size_t ws_size,
                              hipStream_t stream)
{
  const int*   wid   = (const int*)d_in[0];
  const int*   src   = (const int*)d_in[1];
  const int*   dst   = (const int*)d_in[2];
  const int*   n2g   = (const int*)d_in[3];
  const float* emb   = (const float*)d_in[4];
  const float* gatW  = (const float*)d_in[5];
  const float* gatAs = (const float*)d_in[6];
  const float* gatAd = (const float*)d_in[7];
  const float* gatG  = (const float*)d_in[8];
  const float* gatB  = (const float*)d_in[9];
  const float* Wout  = (const float*)d_in[10];
  const float* bout  = (const float*)d_in[11];
  const float* Wih0  = (const float*)d_in[12];
  const float* Whh0  = (const float*)d_in[13];
  const float* bih0  = (const float*)d_in[14];
  const float* bhh0  = (const float*)d_in[15];
  const float* Wih1  = (const float*)d_in[16];
  const float* Whh1  = (const float*)d_in[17];
  const float* bih1  = (const float*)d_in[18];
  const float* bhh1  = (const float*)d_in[19];
  (void)n_in; (void)out_size; (void)ws_size;

  const int N = in_sizes[0];
  const int E = in_sizes[1];
  const int V = in_sizes[4] / HD;

  float* out_newh = (float*)d_out;             // [N,H]
  float* out_read = out_newh + (size_t)N * HD; // [B,H]

  // ---- workspace carve-up (fp32/int32; float4 buffers 16B aligned)
  float* p = (float*)d_ws;
  float* hr    = p; p += (size_t)N * HD;       // per-layer aggregated features
  float* zemb  = p; p += (size_t)V * HD4;      // emb @ [4 layers W]^T
  float* psv   = p; p += 4 * (size_t)V;
  float* pdv   = p; p += 4 * (size_t)V;
  float* cnt   = p; p += NB;                   // cnt+mean1+mean2 contiguous
  float* mean1 = p; p += (size_t)NB * HD;
  float* mean2 = p; p += (size_t)NB * HD;
  float* gi    = p; p += (size_t)NB * HD3;
  float* gh    = p; p += (size_t)NB * HD3;
  float* y0    = p; p += (size_t)NB * HD4;     // [B,2,2H] layer-0 outputs
  float* htA   = p; p += (size_t)NB * HD;
  float* hf1   = p; p += (size_t)NB * HD;
  float* hf2   = p; p += (size_t)NB * HD;
  float* bnsum = p; p += HD;                   // bnsum+bnsq contiguous
  float* bnsq  = p; p += HD;
  float* bnsc  = p; p += HD;
  float* bnsh  = p; p += HD;
  int* deg     = (int*)p; p += N;
  int* rowptr  = (int*)p; p += N + 4;
  int* cursor  = (int*)p; p += N;
  int* swids   = (int*)p; p += E;
  int* bsum    = (int*)p; p += 256;

  auto gemm = [&](const float* A, int lda, const float* asc, const float* ash,
                  const float* W, int ldw, float* C, int ldc, int M, int Nout, int K, int accum) {
    dim3 g((unsigned)((M + TS - 1) / TS), (unsigned)(Nout / TS));
    gemm_tn<<<g, 256, 0, stream>>>(A, lda, asc, ash, W, ldw, C, ldc, M, K, accum);
  };
  auto cell = [&](const float* gi_, const float* gh_, const float* bi, const float* bh,
                  const float* hp, int hld, float* op, int ol) {
    gru_cell<<<(NB * HD + 255) / 256, 256, 0, stream>>>(gi_, gh_, bi, bh, hp, hld, op, ol, NB);
  };

  // ---- CSR by destination (once per call)
  const int nsb = (N + SCB - 1) / SCB;
  hipMemsetAsync(deg, 0, (size_t)N * sizeof(int), stream);
  deg_hist<<<(E + 255) / 256, 256, 0, stream>>>(dst, deg, E);
  scan_bsum<<<nsb, 256, 0, stream>>>(deg, bsum, N);
  scan_small<<<1, 64, 0, stream>>>(bsum, nsb);
  scan_final<<<nsb, 256, 0, stream>>>(deg, bsum, rowptr, N, E);
  hipMemcpyAsync(cursor, rowptr, (size_t)N * sizeof(int), hipMemcpyDeviceToDevice, stream);
  scatter_edges<<<(E + 255) / 256, 256, 0, stream>>>(src, dst, wid, cursor, swids, E);

  // zemb[v, i*H+h] = sum_k emb[v,k] * gat_W[i,h,k]   (gat_W viewed as [4H, H])
  gemm(emb, HD, nullptr, nullptr, gatW, HD, zemb, HD4, V, HD4, HD, 0);
  psv_kernel<<<dim3((V + 3) / 4, 4), 256, 0, stream>>>(zemb, gatAs, gatAd, psv, pdv, V);

  init_newh<<<4096, 256, 0, stream>>>(out_newh, bout, (size_t)N * HD);

  hipMemsetAsync(cnt, 0, (size_t)(NB + 2 * NB * HD) * sizeof(float), stream);
  cnt_kernel<<<(N + 255) / 256, 256, 0, stream>>>(n2g, cnt, N);
  seg_accum<<<N, 256, 0, stream>>>(emb, wid, n2g, mean1, N);
  mean_div<<<(NB * HD + 255) / 256, 256, 0, stream>>>(mean1, cnt, NB * HD);

  for (int l = 0; l < 4; ++l) {
    hipMemsetAsync(bnsum, 0, 2 * HD * sizeof(float), stream);
    gat_node<<<1024, 256, 0, stream>>>(rowptr, swids, wid, psv + (size_t)l * V,
                                       pdv + (size_t)l * V, zemb + (size_t)l * HD,
                                       hr, bnsum, bnsq, N);
    bn_fin<<<1, HD, 0, stream>>>(bnsum, bnsq, gatG + l * HD, gatB + l * HD, bnsc, bnsh, 1.f / (float)N);
    // new_h += BN(hr) @ W_out[:, l*H:(l+1)*H]^T  (BN fused into A-load)
    gemm(hr, HD, bnsc, bnsh, Wout + l * HD, HD4, out_newh, HD, N, HD, HD, 1);
  }

  seg_accum<<<N, 256, 0, stream>>>(out_newh, nullptr, n2g, mean2, N);
  mean_div<<<(NB * HD + 255) / 256, 256, 0, stream>>>(mean2, cnt, NB * HD);

  // ---- GRU (T=2, 2 layers, bidirectional). y0[b,t,c]: c = t*2H + dir*H + h
  // layer0 forward
  gemm(mean1, HD, nullptr, nullptr, Wih0, HD, gi, HD3, NB, HD3, HD, 0);
  cell(gi, nullptr, bih0, bhh0, nullptr, 0, y0 + 0, HD4);
  gemm(mean2, HD, nullptr, nullptr, Wih0, HD, gi, HD3, NB, HD3, HD, 0);
  gemm(y0 + 0, HD4, nullptr, nullptr, Whh0, HD, gh, HD3, NB, HD3, HD, 0);
  cell(gi, gh, bih0, bhh0, y0 + 0, HD4, y0 + HD2, HD4);
  // layer0 backward
  const float* Wih0b = Wih0 + (size_t)HD3 * HD;
  const float* Whh0b = Whh0 + (size_t)HD3 * HD;
  gemm(mean2, HD, nullptr, nullptr, Wih0b, HD, gi, HD3, NB, HD3, HD, 0);
  cell(gi, nullptr, bih0 + HD3, bhh0 + HD3, nullptr, 0, y0 + HD2 + HD, HD4);
  gemm(mean1, HD, nullptr, nullptr, Wih0b, HD, gi, HD3, NB, HD3, HD, 0);
  gemm(y0 + HD2 + HD, HD4, nullptr, nullptr, Whh0b, HD, gh, HD3, NB, HD3, HD, 0);
  cell(gi, gh, bih0 + HD3, bhh0 + HD3, y0 + HD2 + HD, HD4, y0 + HD, HD4);
  // layer1 forward (input = y0[:,t,:] of width 2H)
  gemm(y0 + 0, HD4, nullptr, nullptr, Wih1, HD2, gi, HD3, NB, HD3, HD2, 0);
  cell(gi, nullptr, bih1, bhh1, nullptr, 0, htA, HD);
  gemm(y0 + HD2, HD4, nullptr, nullptr, Wih1, HD2, gi, HD3, NB, HD3, HD2, 0);
  gemm(htA, HD, nullptr, nullptr, Whh1, HD, gh, HD3, NB, HD3, HD, 0);
  cell(gi, gh, bih1, bhh1, htA, HD, hf1, HD);
  // layer1 backward
  const float* Wih1b = Wih1 + (size_t)HD3 * HD2;
  const float* Whh1b = Whh1 + (size_t)HD3 * HD;
  gemm(y0 + HD2, HD4, nullptr, nullptr, Wih1b, HD2, gi, HD3, NB, HD3, HD2, 0);
  cell(gi, nullptr, bih1 + HD3, bhh1 + HD3, nullptr, 0, htA, HD);
  gemm(y0 + 0, HD4, nullptr, nullptr, Wih1b, HD2, gi, HD3, NB, HD3, HD2, 0);
  gemm(htA, HD, nullptr, nullptr, Whh1b, HD, gh, HD3, NB, HD3, HD, 0);
  cell(gi, gh, bih1 + HD3, bhh1 + HD3, htA, HD, hf2, HD);

  readout_k<<<(NB * HD + 255) / 256, 256, 0, stream>>>(y0, hf1, hf2, out_read, NB);
}

// Round 3
// 1609.278 us; speedup vs baseline: 3.2149x; 1.6864x over previous
//
#include <hip/hip_runtime.h>
#include <hip/hip_bf16.h>

#define HD  256
#define HD2 512
#define HD3 768
#define HD4 1024
#define NB  4096   // number of graphs (B)

static __device__ __forceinline__ float lrelu(float x) { return x >= 0.f ? x : 0.01f * x; }
static __device__ __forceinline__ unsigned short rne_bf16(float f) {
  unsigned u = __float_as_uint(f);
  u += 0x7FFF + ((u >> 16) & 1);
  return (unsigned short)(u >> 16);
}

typedef short v8s __attribute__((ext_vector_type(8)));
typedef float v4f __attribute__((ext_vector_type(4)));

#define GLD16(gp, lp) __builtin_amdgcn_global_load_lds( \
    (const __attribute__((address_space(1))) void*)(gp), \
    (__attribute__((address_space(3))) void*)(lp), 16, 0, 0)

// ---------------- bf16 MFMA GEMM: C[M,Nout] (+)= A[M,K]bf16 @ B[Nout,K]bf16^T + shift[col]
// 128x128 tile, BK=32, 4 waves (2x2), each wave 64x64 via 4x4 16x16x32 frags (m97 structure)
__global__ __launch_bounds__(256)
void gemm_mfma(const unsigned short* __restrict__ A, int lda,
               const unsigned short* __restrict__ B, int ldb,
               const float* __restrict__ shiftv,
               float* __restrict__ C, int ldc,
               int M, int K, int accumulate)
{
  __shared__ unsigned short Asw[128 * 32];
  __shared__ unsigned short Bsw[128 * 32];
  const int tid = threadIdx.x;
  const int lane = tid & 63, w = tid >> 6;
  const int bm = blockIdx.x * 128, bn = blockIdx.y * 128;
  const int wr = w >> 1, wc = w & 1;
  const int lrow = lane >> 2;          // staging: row within 16-row chunk
  const int lke  = (lane & 3) * 8;     // staging: element offset (8 bf16 = 16B)
  const int fr = lane & 15, fk = (lane >> 4) * 8;   // fragment coords
  v4f acc[4][4] = {};
  for (int k0 = 0; k0 < K; k0 += 32) {
    #pragma unroll
    for (int i = 0; i < 2; ++i) {
      const int row = w * 32 + i * 16 + lrow;
      int grow = bm + row; grow = grow < M ? grow : M - 1;
      GLD16(A + (size_t)grow * lda + k0 + lke, &Asw[(w * 32 + i * 16) * 32]);
      GLD16(B + (size_t)(bn + row) * ldb + k0 + lke, &Bsw[(w * 32 + i * 16) * 32]);
    }
    __syncthreads();
    v8s a[4], b[4];
    #pragma unroll
    for (int m = 0; m < 4; ++m) a[m] = *(const v8s*)&Asw[(wr * 64 + m * 16 + fr) * 32 + fk];
    #pragma unroll
    for (int n = 0; n < 4; ++n) b[n] = *(const v8s*)&Bsw[(wc * 64 + n * 16 + fr) * 32 + fk];
    #pragma unroll
    for (int m = 0; m < 4; ++m)
      #pragma unroll
      for (int n = 0; n < 4; ++n)
        acc[m][n] = __builtin_amdgcn_mfma_f32_16x16x32_bf16(a[m], b[n], acc[m][n], 0, 0, 0);
    __syncthreads();
  }
  const int cr = (lane >> 4) * 4;  // C frag: row=(lane>>4)*4+r, col=lane&15 (m89-verified)
  const int cc = lane & 15;
  #pragma unroll
  for (int m = 0; m < 4; ++m) {
    #pragma unroll
    for (int r = 0; r < 4; ++r) {
      const int row = bm + wr * 64 + m * 16 + cr + r;
      if (row < M) {
        float* cp = C + (size_t)row * ldc + bn + wc * 64 + cc;
        #pragma unroll
        for (int n = 0; n < 4; ++n) {
          float v = acc[m][n][r] + shiftv[bn + wc * 64 + n * 16 + cc];
          if (accumulate) v += cp[n * 16];
          cp[n * 16] = v;
        }
      }
    }
  }
}

// Wp[n,k] = bf16(Wout[n,k]*sc[k]);  shiftv[n] = (bout?bout[n]:0) + sum_k sh[k]*Wout[n,k]
__global__ __launch_bounds__(256)
void fold_w(const float* __restrict__ Wout, int ldw,
            const float* __restrict__ sc, const float* __restrict__ sh,
            const float* __restrict__ bout,
            unsigned short* __restrict__ Wp, int ldp,
            float* __restrict__ shiftv, int K)
{
  const int n = blockIdx.x;
  const int t = threadIdx.x;
  float s = 0.f;
  for (int k = t; k < K; k += 256) {
    float wv = Wout[(size_t)n * ldw + k];
    s = fmaf(sh[k], wv, s);
    Wp[(size_t)n * ldp + k] = rne_bf16(wv * sc[k]);
  }
  __shared__ float red[256];
  red[t] = s; __syncthreads();
  for (int o = 128; o; o >>= 1) { if (t < o) red[t] += red[t + o]; __syncthreads(); }
  if (t == 0) shiftv[n] = red[0] + (bout ? bout[n] : 0.f);
}

// ---------------- generic fp32 GEMM (GRU + zemb): C[M,Nout] = A[M,K] @ W[Nout,K]^T
#define TS 64
#define KS 16
__global__ __launch_bounds__(256)
void gemm_tn(const float* __restrict__ A, int lda,
             const float* __restrict__ W, int ldw,
             float* __restrict__ C, int ldc,
             int M, int K)
{
  __shared__ float As[KS][TS + 1];
  __shared__ float Ws[KS][TS + 1];
  const int tid = threadIdx.x;
  const int bm = blockIdx.x * TS;
  const int bn = blockIdx.y * TS;
  const int r  = tid >> 2;
  const int kc = (tid & 3) << 2;
  const int tm = (tid >> 4) << 2;
  const int tn = (tid & 15) << 2;
  float acc[4][4] = {};
  for (int k0 = 0; k0 < K; k0 += KS) {
    float4 av = make_float4(0.f, 0.f, 0.f, 0.f);
    const int row = bm + r;
    if (row < M) av = *(const float4*)(A + (size_t)row * lda + k0 + kc);
    As[kc + 0][r] = av.x; As[kc + 1][r] = av.y; As[kc + 2][r] = av.z; As[kc + 3][r] = av.w;
    float4 wv = *(const float4*)(W + (size_t)(bn + r) * ldw + k0 + kc);
    Ws[kc + 0][r] = wv.x; Ws[kc + 1][r] = wv.y; Ws[kc + 2][r] = wv.z; Ws[kc + 3][r] = wv.w;
    __syncthreads();
    #pragma unroll
    for (int kk = 0; kk < KS; ++kk) {
      float a_[4], b_[4];
      #pragma unroll
      for (int i = 0; i < 4; ++i) a_[i] = As[kk][tm + i];
      #pragma unroll
      for (int j = 0; j < 4; ++j) b_[j] = Ws[kk][tn + j];
      #pragma unroll
      for (int i = 0; i < 4; ++i)
        #pragma unroll
        for (int j = 0; j < 4; ++j) acc[i][j] = fmaf(a_[i], b_[j], acc[i][j]);
    }
    __syncthreads();
  }
  #pragma unroll
  for (int i = 0; i < 4; ++i) {
    const int row = bm + tm + i;
    if (row < M)
      *(float4*)(C + (size_t)row * ldc + bn + tn) =
          make_float4(acc[i][0], acc[i][1], acc[i][2], acc[i][3]);
  }
}

// per-vocab attention scalars
__global__ __launch_bounds__(256)
void psv_kernel(const float* __restrict__ zemb, const float* __restrict__ as_,
                const float* __restrict__ ad_, float* __restrict__ psv,
                float* __restrict__ pdv, int V)
{
  int v = (int)((blockIdx.x * 256u + threadIdx.x) >> 6);
  int l = blockIdx.y;
  int lane = threadIdx.x & 63;
  if (v >= V) return;
  float4 zv = ((const float4*)(zemb + (size_t)v * HD4 + (size_t)l * HD))[lane];
  float4 a  = ((const float4*)(as_ + (size_t)l * HD))[lane];
  float4 b  = ((const float4*)(ad_ + (size_t)l * HD))[lane];
  float s = zv.x * a.x + zv.y * a.y + zv.z * a.z + zv.w * a.w;
  float d = zv.x * b.x + zv.y * b.y + zv.z * b.z + zv.w * b.w;
  #pragma unroll
  for (int o = 32; o; o >>= 1) { s += __shfl_down(s, o); d += __shfl_down(d, o); }
  if (lane == 0) { psv[(size_t)l * V + v] = s; pdv[(size_t)l * V + v] = d; }
}

__global__ void init_newh(float* __restrict__ out, const float* __restrict__ bout, size_t total) {
  size_t i = (size_t)blockIdx.x * 256 + threadIdx.x;
  size_t st = (size_t)gridDim.x * 256;
  for (; i < total; i += st) out[i] = bout[i & (HD - 1)];
}

__global__ void cnt_kernel(const int* __restrict__ n2g, float* __restrict__ cnt, int N) {
  int n = blockIdx.x * 256 + threadIdx.x;
  if (n < N) unsafeAtomicAdd(&cnt[n2g[n]], 1.f);
}

__global__ __launch_bounds__(256)
void seg_accum(const float* __restrict__ X, const int* __restrict__ gather,
               const int* __restrict__ n2g, float* __restrict__ acc, int N)
{
  int n = blockIdx.x;
  if (n >= N) return;
  int h = threadIdx.x;
  int row = gather ? gather[n] : n;
  unsafeAtomicAdd(&acc[(size_t)n2g[n] * HD + h], X[(size_t)row * HD + h]);
}

__global__ void mean_div(float* __restrict__ acc, const float* __restrict__ cnt, int total) {
  int i = blockIdx.x * 256 + threadIdx.x;
  if (i < total) acc[i] /= fmaxf(cnt[i >> 8], 1.f);
}

// ---------------- CSR build (by dst) ----------------
__global__ void deg_hist(const int* __restrict__ dst, int* __restrict__ deg, int E) {
  int e = blockIdx.x * 256 + threadIdx.x;
  if (e < E) atomicAdd(&deg[dst[e]], 1);
}

#define SCB 1024
__global__ void scan_bsum(const int* __restrict__ deg, int* __restrict__ bsum, int N) {
  __shared__ int sh[256];
  int base = blockIdx.x * SCB;
  int t = threadIdx.x;
  int s = 0;
  for (int i = t; i < SCB; i += 256) { int idx = base + i; s += (idx < N) ? deg[idx] : 0; }
  sh[t] = s; __syncthreads();
  for (int o = 128; o; o >>= 1) { if (t < o) sh[t] += sh[t + o]; __syncthreads(); }
  if (t == 0) bsum[blockIdx.x] = sh[0];
}
__global__ void scan_small(int* __restrict__ bsum, int nb) {
  if (threadIdx.x == 0) {
    int acc = 0;
    for (int i = 0; i < nb; ++i) { int v = bsum[i]; bsum[i] = acc; acc += v; }
  }
}
__global__ void scan_final(const int* __restrict__ deg, const int* __restrict__ bsum,
                           int* __restrict__ rowptr, int N, int E) {
  __shared__ int sh[256];
  int base = blockIdx.x * SCB;
  int t = threadIdx.x;
  int idx0 = base + t * 4;
  int v[4]; int s = 0;
  #pragma unroll
  for (int j = 0; j < 4; ++j) { int idx = idx0 + j; v[j] = (idx < N) ? deg[idx] : 0; s += v[j]; }
  sh[t] = s; __syncthreads();
  for (int o = 1; o < 256; o <<= 1) {
    int x = (t >= o) ? sh[t - o] : 0;
    __syncthreads();
    sh[t] += x;
    __syncthreads();
  }
  int off = bsum[blockIdx.x] + ((t == 0) ? 0 : sh[t - 1]);
  #pragma unroll
  for (int j = 0; j < 4; ++j) {
    int idx = idx0 + j;
    if (idx < N) rowptr[idx] = off;
    off += v[j];
  }
  if (idx0 <= N - 1 && N - 1 < idx0 + 4) rowptr[N] = E;
}
__global__ void scatter_edges(const int* __restrict__ src, const int* __restrict__ dst,
                              const int* __restrict__ wid, int* __restrict__ cursor,
                              int* __restrict__ swids, int E) {
  int e = blockIdx.x * 256 + threadIdx.x;
  if (e >= E) return;
  int pos = atomicAdd(&cursor[dst[e]], 1);
  swids[pos] = wid[src[e]];
}

// ---------------- fused per-layer GAT -> bf16 output + BN partials
__global__ __launch_bounds__(256)
void gat_node(const int* __restrict__ rowptr, const int* __restrict__ swids,
              const int* __restrict__ wid, const float* __restrict__ psv_l,
              const float* __restrict__ pdv_l, const float* __restrict__ zl,
              unsigned short* __restrict__ hb, int ldh,
              float* __restrict__ bs, float* __restrict__ bq, int N)
{
  const int lane = threadIdx.x & 63;
  const int wv   = threadIdx.x >> 6;
  const int gw   = blockIdx.x * 4 + wv;
  const int nw   = gridDim.x * 4;
  float sreg[4] = {}, qreg[4] = {};
  for (int n = gw; n < N; n += nw) {
    const int b0 = rowptr[n], b1 = rowptr[n + 1];
    const float pdn = pdv_l[wid[n]];
    float m = -INFINITY;
    for (int i = b0; i < b1; ++i) m = fmaxf(m, lrelu(psv_l[swids[i]] + pdn));
    if (b0 == b1) m = 0.f;
    float s = 0.f;
    float4 acc = make_float4(0.f, 0.f, 0.f, 0.f);
    for (int i = b0; i < b1; ++i) {
      const int sw = swids[i];
      const float ex = expf(lrelu(psv_l[sw] + pdn) - m);
      s += ex;
      float4 zv = ((const float4*)(zl + (size_t)sw * HD4))[lane];
      acc.x = fmaf(ex, zv.x, acc.x);
      acc.y = fmaf(ex, zv.y, acc.y);
      acc.z = fmaf(ex, zv.z, acc.z);
      acc.w = fmaf(ex, zv.w, acc.w);
    }
    const float inv = 1.f / (s == 0.f ? 1.f : s);
    float4 v;
    v.x = fmaxf(acc.x * inv, 0.f);
    v.y = fmaxf(acc.y * inv, 0.f);
    v.z = fmaxf(acc.z * inv, 0.f);
    v.w = fmaxf(acc.w * inv, 0.f);
    ushort4 o;
    o.x = rne_bf16(v.x); o.y = rne_bf16(v.y); o.z = rne_bf16(v.z); o.w = rne_bf16(v.w);
    ((ushort4*)(hb + (size_t)n * ldh))[lane] = o;
    sreg[0] += v.x; sreg[1] += v.y; sreg[2] += v.z; sreg[3] += v.w;
    qreg[0] = fmaf(v.x, v.x, qreg[0]); qreg[1] = fmaf(v.y, v.y, qreg[1]);
    qreg[2] = fmaf(v.z, v.z, qreg[2]); qreg[3] = fmaf(v.w, v.w, qreg[3]);
  }
  __shared__ float ls[4][64][4];
  __shared__ float lq[4][64][4];
  #pragma unroll
  for (int j = 0; j < 4; ++j) { ls[wv][lane][j] = sreg[j]; lq[wv][lane][j] = qreg[j]; }
  __syncthreads();
  if (wv == 0) {
    #pragma unroll
    for (int j = 0; j < 4; ++j) {
      float s4 = ls[0][lane][j] + ls[1][lane][j] + ls[2][lane][j] + ls[3][lane][j];
      float q4 = lq[0][lane][j] + lq[1][lane][j] + lq[2][lane][j] + lq[3][lane][j];
      unsafeAtomicAdd(&bs[lane * 4 + j], s4);
      unsafeAtomicAdd(&bq[lane * 4 + j], q4);
    }
  }
}

__global__ void bn_fin(const float* __restrict__ bs, const float* __restrict__ bq,
                       const float* __restrict__ gamma, const float* __restrict__ beta,
                       float* __restrict__ sc, float* __restrict__ sh, float invN)
{
  int h = threadIdx.x;
  float mu  = bs[h] * invN;
  float var = fmaxf(bq[h] * invN - mu * mu, 0.f);
  float s = gamma[h] * rsqrtf(var + 1e-5f);
  sc[h] = s;
  sh[h] = fmaf(-mu, s, beta[h]);
}

__global__ __launch_bounds__(256)
void gru_cell(const float* __restrict__ gi, const float* __restrict__ gh,
              const float* __restrict__ bih, const float* __restrict__ bhh,
              const float* __restrict__ hprev, int hld,
              float* __restrict__ out, int outld, int Bn)
{
  int i = blockIdx.x * 256 + threadIdx.x;
  if (i >= Bn * HD) return;
  int b = i >> 8, h = i & 255;
  const float* gr = gi + (size_t)b * HD3;
  float ir  = gr[h]       + bih[h];
  float iz  = gr[HD + h]  + bih[HD + h];
  float in_ = gr[HD2 + h] + bih[HD2 + h];
  float hrv = bhh[h], hzv = bhh[HD + h], hnv = bhh[HD2 + h];
  if (gh) {
    const float* gg = gh + (size_t)b * HD3;
    hrv += gg[h]; hzv += gg[HD + h]; hnv += gg[HD2 + h];
  }
  float hp = hprev ? hprev[(size_t)b * hld + h] : 0.f;
  float rg = 1.f / (1.f + expf(-(ir + hrv)));
  float zg = 1.f / (1.f + expf(-(iz + hzv)));
  float n  = tanhf(fmaf(rg, hnv, in_));
  out[(size_t)b * outld + h] = (1.f - zg) * n + zg * hp;
}

__global__ void readout_k(const float* __restrict__ y0, const float* __restrict__ hf1,
                          const float* __restrict__ hf2, float* __restrict__ out, int Bn)
{
  int i = blockIdx.x * 256 + threadIdx.x;
  if (i >= Bn * HD) return;
  int b = i >> 8, h = i & 255;
  out[i] = y0[(size_t)b * HD4 + HD2 + h] + y0[(size_t)b * HD4 + HD + h] + hf1[i] + hf2[i];
}

extern "C" void kernel_launch(void* const* d_in, const int* in_sizes, int n_in,
                              void* d_out, int out_size, void* d_ws, size_t ws_size,
                              hipStream_t stream)
{
  const int*   wid   = (const int*)d_in[0];
  const int*   src   = (const int*)d_in[1];
  const int*   dst   = (const int*)d_in[2];
  const int*   n2g   = (const int*)d_in[3];
  const float* emb   = (const float*)d_in[4];
  const float* gatW  = (const float*)d_in[5];
  const float* gatAs = (const float*)d_in[6];
  const float* gatAd = (const float*)d_in[7];
  const float* gatG  = (const float*)d_in[8];
  const float* gatB  = (const float*)d_in[9];
  const float* Wout  = (const float*)d_in[10];
  const float* bout  = (const float*)d_in[11];
  const float* Wih0  = (const float*)d_in[12];
  const float* Whh0  = (const float*)d_in[13];
  const float* bih0  = (const float*)d_in[14];
  const float* bhh0  = (const float*)d_in[15];
  const float* Wih1  = (const float*)d_in[16];
  const float* Whh1  = (const float*)d_in[17];
  const float* bih1  = (const float*)d_in[18];
  const float* bhh1  = (const float*)d_in[19];
  (void)n_in; (void)out_size;

  const int N = in_sizes[0];
  const int E = in_sizes[1];
  const int V = in_sizes[4] / HD;

  float* out_newh = (float*)d_out;
  float* out_read = out_newh + (size_t)N * HD;

  // ---- workspace carve-up (256B-aligned allocs); habf last (size depends on path)
  char* cp  = (char*)d_ws;
  char* wse = (char*)d_ws + ws_size;
  auto alloc = [&](size_t bytes) { char* r = cp; cp += (bytes + 255) & ~(size_t)255; return r; };
  float* zemb  = (float*)alloc((size_t)V * HD4 * 4);
  float* psv   = (float*)alloc(4 * (size_t)V * 4);
  float* pdv   = (float*)alloc(4 * (size_t)V * 4);
  float* cnt   = (float*)alloc(((size_t)NB + 2 * (size_t)NB * HD) * 4);  // cnt|mean1|mean2
  float* mean1 = cnt + NB;
  float* mean2 = mean1 + (size_t)NB * HD;
  float* gi    = (float*)alloc((size_t)NB * HD3 * 4);
  float* gh    = (float*)alloc((size_t)NB * HD3 * 4);
  float* y0    = (float*)alloc((size_t)NB * HD4 * 4);
  float* htA   = (float*)alloc((size_t)NB * HD * 4);
  float* hf1   = (float*)alloc((size_t)NB * HD * 4);
  float* hf2   = (float*)alloc((size_t)NB * HD * 4);
  float* bnsum = (float*)alloc(4096 * 4);            // bnsum[1024]|bnsq[1024] contiguous + sc,sh
  float* bnsq  = bnsum + 1024;
  float* bnsc  = (float*)alloc(1024 * 4);
  float* bnsh  = (float*)alloc(1024 * 4);
  unsigned short* Wp = (unsigned short*)alloc((size_t)HD * HD4 * 2);
  float* shiftv = (float*)alloc(HD * 4);
  int* deg     = (int*)alloc((size_t)N * 4);
  int* rowptr  = (int*)alloc((size_t)(N + 4) * 4);
  int* cursor  = (int*)alloc((size_t)N * 4);
  int* swids   = (int*)alloc((size_t)E * 4);
  int* bsum    = (int*)alloc(256 * 4);
  unsigned short* habf = (unsigned short*)cp;
  const bool bigA = (cp + (size_t)N * HD4 * 2 + 256) <= wse;  // combined [N,1024] bf16 fits?

  auto gemm32 = [&](const float* A, int lda, const float* W, int ldw,
                    float* C, int ldc, int M, int Nout, int K) {
    dim3 g((unsigned)((M + TS - 1) / TS), (unsigned)(Nout / TS));
    gemm_tn<<<g, 256, 0, stream>>>(A, lda, W, ldw, C, ldc, M, K);
  };
  auto cell = [&](const float* gi_, const float* gh_, const float* bi, const float* bh,
                  const float* hp, int hld, float* op, int ol) {
    gru_cell<<<(NB * HD + 255) / 256, 256, 0, stream>>>(gi_, gh_, bi, bh, hp, hld, op, ol, NB);
  };

  // ---- CSR by destination
  const int nsb = (N + SCB - 1) / SCB;
  hipMemsetAsync(deg, 0, (size_t)N * sizeof(int), stream);
  deg_hist<<<(E + 255) / 256, 256, 0, stream>>>(dst, deg, E);
  scan_bsum<<<nsb, 256, 0, stream>>>(deg, bsum, N);
  scan_small<<<1, 64, 0, stream>>>(bsum, nsb);
  scan_final<<<nsb, 256, 0, stream>>>(deg, bsum, rowptr, N, E);
  hipMemcpyAsync(cursor, rowptr, (size_t)N * sizeof(int), hipMemcpyDeviceToDevice, stream);
  scatter_edges<<<(E + 255) / 256, 256, 0, stream>>>(src, dst, wid, cursor, swids, E);

  // zemb = emb @ [4 layers W]^T ;  per-vocab attention scalars
  gemm32(emb, HD, gatW, HD, zemb, HD4, V, HD4, HD);
  psv_kernel<<<dim3((V + 3) / 4, 4), 256, 0, stream>>>(zemb, gatAs, gatAd, psv, pdv, V);

  hipMemsetAsync(cnt, 0, (size_t)(NB + 2 * NB * HD) * sizeof(float), stream);
  cnt_kernel<<<(N + 255) / 256, 256, 0, stream>>>(n2g, cnt, N);
  seg_accum<<<N, 256, 0, stream>>>(emb, wid, n2g, mean1, N);
  mean_div<<<(NB * HD + 255) / 256, 256, 0, stream>>>(mean1, cnt, NB * HD);

  hipMemsetAsync(bnsum, 0, 2048 * sizeof(float), stream);
  if (bigA) {
    // combined: habf[N,1024] = bf16 concat of 4 layers; one K=1024 MFMA GEMM
    for (int l = 0; l < 4; ++l) {
      gat_node<<<1024, 256, 0, stream>>>(rowptr, swids, wid, psv + (size_t)l * V,
                                         pdv + (size_t)l * V, zemb + (size_t)l * HD,
                                         habf + (size_t)l * HD, HD4,
                                         bnsum + l * HD, bnsq + l * HD, N);
      bn_fin<<<1, HD, 0, stream>>>(bnsum + l * HD, bnsq + l * HD, gatG + l * HD,
                                   gatB + l * HD, bnsc + l * HD, bnsh + l * HD, 1.f / (float)N);
    }
    fold_w<<<HD, 256, 0, stream>>>(Wout, HD4, bnsc, bnsh, bout, Wp, HD4, shiftv, HD4);
    gemm_mfma<<<dim3((N + 127) / 128, 2), 256, 0, stream>>>(habf, HD4, Wp, HD4, shiftv,
                                                            out_newh, HD, N, HD4, 0);
  } else {
    // fallback: per-layer [N,256] bf16 buffer + 4 accumulate GEMMs
    init_newh<<<4096, 256, 0, stream>>>(out_newh, bout, (size_t)N * HD);
    for (int l = 0; l < 4; ++l) {
      gat_node<<<1024, 256, 0, stream>>>(rowptr, swids, wid, psv + (size_t)l * V,
                                         pdv + (size_t)l * V, zemb + (size_t)l * HD,
                                         habf, HD, bnsum + l * HD, bnsq + l * HD, N);
      bn_fin<<<1, HD, 0, stream>>>(bnsum + l * HD, bnsq + l * HD, gatG + l * HD,
                                   gatB + l * HD, bnsc + l * HD, bnsh + l * HD, 1.f / (float)N);
      fold_w<<<HD, 256, 0, stream>>>(Wout + (size_t)l * HD, HD4, bnsc + l * HD, bnsh + l * HD,
                                     nullptr, Wp, HD, shiftv, HD);
      gemm_mfma<<<dim3((N + 127) / 128, 2), 256, 0, stream>>>(habf, HD, Wp, HD, shiftv,
                                                              out_newh, HD, N, HD, 1);
    }
  }

  seg_accum<<<N, 256, 0, stream>>>(out_newh, nullptr, n2g, mean2, N);
  mean_div<<<(NB * HD + 255) / 256, 256, 0, stream>>>(mean2, cnt, NB * HD);

  // ---- GRU (T=2, 2 layers, bidirectional). y0[b,t,c]: c = t*2H + dir*H + h
  gemm32(mean1, HD, Wih0, HD, gi, HD3, NB, HD3, HD);
  cell(gi, nullptr, bih0, bhh0, nullptr, 0, y0 + 0, HD4);
  gemm32(mean2, HD, Wih0, HD, gi, HD3, NB, HD3, HD);
  gemm32(y0 + 0, HD4, Whh0, HD, gh, HD3, NB, HD3, HD);
  cell(gi, gh, bih0, bhh0, y0 + 0, HD4, y0 + HD2, HD4);
  const float* Wih0b = Wih0 + (size_t)HD3 * HD;
  const float* Whh0b = Whh0 + (size_t)HD3 * HD;
  gemm32(mean2, HD, Wih0b, HD, gi, HD3, NB, HD3, HD);
  cell(gi, nullptr, bih0 + HD3, bhh0 + HD3, nullptr, 0, y0 + HD2 + HD, HD4);
  gemm32(mean1, HD, Wih0b, HD, gi, HD3, NB, HD3, HD);
  gemm32(y0 + HD2 + HD, HD4, Whh0b, HD, gh, HD3, NB, HD3, HD);
  cell(gi, gh, bih0 + HD3, bhh0 + HD3, y0 + HD2 + HD, HD4, y0 + HD, HD4);
  gemm32(y0 + 0, HD4, Wih1, HD2, gi, HD3, NB, HD3, HD2);
  cell(gi, nullptr, bih1, bhh1, nullptr, 0, htA, HD);
  gemm32(y0 + HD2, HD4, Wih1, HD2, gi, HD3, NB, HD3, HD2);
  gemm32(htA, HD, Whh1, HD, gh, HD3, NB, HD3, HD);
  cell(gi, gh, bih1, bhh1, htA, HD, hf1, HD);
  const float* Wih1b = Wih1 + (size_t)HD3 * HD2;
  const float* Whh1b = Whh1 + (size_t)HD3 * HD;
  gemm32(y0 + HD2, HD4, Wih1b, HD2, gi, HD3, NB, HD3, HD2);
  cell(gi, nullptr, bih1 + HD3, bhh1 + HD3, nullptr, 0, htA, HD);
  gemm32(y0 + 0, HD4, Wih1b, HD2, gi, HD3, NB, HD3, HD2);
  gemm32(htA, HD, Whh1b, HD, gh, HD3, NB, HD3, HD);
  cell(gi, gh, bih1 + HD3, bhh1 + HD3, htA, HD, hf2, HD);

  readout_k<<<(NB * HD + 255) / 256, 256, 0, stream>>>(y0, hf1, hf2, out_read, NB);
}

// Round 5
// 811.565 us; speedup vs baseline: 6.3749x; 1.9829x over previous
//
#include <hip/hip_runtime.h>
#include <hip/hip_bf16.h>

#define HD  256
#define HD2 512
#define HD3 768
#define HD4 1024
#define NB  4096   // number of graphs (B)

static __device__ __forceinline__ float lrelu(float x) { return x >= 0.f ? x : 0.01f * x; }
static __device__ __forceinline__ unsigned short rne_bf16(float f) {
  unsigned u = __float_as_uint(f);
  u += 0x7FFF + ((u >> 16) & 1);
  return (unsigned short)(u >> 16);
}

typedef short v8s __attribute__((ext_vector_type(8)));
typedef float v4f __attribute__((ext_vector_type(4)));

#define GLD16(gp, lp) __builtin_amdgcn_global_load_lds( \
    (const __attribute__((address_space(1))) void*)(gp), \
    (__attribute__((address_space(3))) void*)(lp), 16, 0, 0)

// ---------------- bf16 MFMA GEMM: C[M,Nout] (+)= A[M,K]bf16 @ B[Nout,K]bf16^T (+ shift[col])
// 128x128 tile, BK=32, 4 waves (2x2), each wave 64x64 via 4x4 16x16x32 frags (m97 structure)
__global__ __launch_bounds__(256)
void gemm_mfma(const unsigned short* __restrict__ A, int lda,
               const unsigned short* __restrict__ B, int ldb,
               const float* __restrict__ shiftv,
               float* __restrict__ C, int ldc,
               int M, int K, int accumulate)
{
  __shared__ unsigned short Asw[128 * 32];
  __shared__ unsigned short Bsw[128 * 32];
  const int tid = threadIdx.x;
  const int lane = tid & 63, w = tid >> 6;
  const int bm = blockIdx.x * 128, bn = blockIdx.y * 128;
  const int wr = w >> 1, wc = w & 1;
  const int lrow = lane >> 2;          // staging: row within 16-row chunk
  const int lke  = (lane & 3) * 8;     // staging: element offset (8 bf16 = 16B)
  const int fr = lane & 15, fk = (lane >> 4) * 8;   // fragment coords
  v4f acc[4][4] = {};
  for (int k0 = 0; k0 < K; k0 += 32) {
    #pragma unroll
    for (int i = 0; i < 2; ++i) {
      const int row = w * 32 + i * 16 + lrow;
      int grow = bm + row; grow = grow < M ? grow : M - 1;
      GLD16(A + (size_t)grow * lda + k0 + lke, &Asw[(w * 32 + i * 16) * 32]);
      GLD16(B + (size_t)(bn + row) * ldb + k0 + lke, &Bsw[(w * 32 + i * 16) * 32]);
    }
    __syncthreads();
    v8s a[4], b[4];
    #pragma unroll
    for (int m = 0; m < 4; ++m) a[m] = *(const v8s*)&Asw[(wr * 64 + m * 16 + fr) * 32 + fk];
    #pragma unroll
    for (int n = 0; n < 4; ++n) b[n] = *(const v8s*)&Bsw[(wc * 64 + n * 16 + fr) * 32 + fk];
    #pragma unroll
    for (int m = 0; m < 4; ++m)
      #pragma unroll
      for (int n = 0; n < 4; ++n)
        acc[m][n] = __builtin_amdgcn_mfma_f32_16x16x32_bf16(a[m], b[n], acc[m][n], 0, 0, 0);
    __syncthreads();
  }
  const int cr = (lane >> 4) * 4;  // C frag: row=(lane>>4)*4+r, col=lane&15 (m89-verified)
  const int cc = lane & 15;
  #pragma unroll
  for (int m = 0; m < 4; ++m) {
    #pragma unroll
    for (int r = 0; r < 4; ++r) {
      const int row = bm + wr * 64 + m * 16 + cr + r;
      if (row < M) {
        float* cp = C + (size_t)row * ldc + bn + wc * 64 + cc;
        #pragma unroll
        for (int n = 0; n < 4; ++n) {
          float v = acc[m][n][r];
          if (shiftv) v += shiftv[bn + wc * 64 + n * 16 + cc];
          if (accumulate) v += cp[n * 16];
          cp[n * 16] = v;
        }
      }
    }
  }
}

// Wp[n,k] = bf16(Wout[n,k]*sc[k]);  shiftv[n] = (bout?bout[n]:0) + sum_k sh[k]*Wout[n,k]
__global__ __launch_bounds__(256)
void fold_w(const float* __restrict__ Wout, int ldw,
            const float* __restrict__ sc, const float* __restrict__ sh,
            const float* __restrict__ bout,
            unsigned short* __restrict__ Wp, int ldp,
            float* __restrict__ shiftv, int K)
{
  const int n = blockIdx.x;
  const int t = threadIdx.x;
  float s = 0.f;
  for (int k = t; k < K; k += 256) {
    float wv = Wout[(size_t)n * ldw + k];
    s = fmaf(sh[k], wv, s);
    Wp[(size_t)n * ldp + k] = rne_bf16(wv * sc[k]);
  }
  __shared__ float red[256];
  red[t] = s; __syncthreads();
  for (int o = 128; o; o >>= 1) { if (t < o) red[t] += red[t + o]; __syncthreads(); }
  if (t == 0) shiftv[n] = red[0] + (bout ? bout[n] : 0.f);
}

__global__ void f2b_kernel(const float* __restrict__ src, unsigned short* __restrict__ dst, int n) {
  int i = blockIdx.x * 256 + threadIdx.x;
  if (i < n) dst[i] = rne_bf16(src[i]);
}

// ---------------- generic fp32 GEMM (zemb only): C[M,Nout] = A[M,K] @ W[Nout,K]^T
#define TS 64
#define KS 16
__global__ __launch_bounds__(256)
void gemm_tn(const float* __restrict__ A, int lda,
             const float* __restrict__ W, int ldw,
             float* __restrict__ C, int ldc,
             int M, int K)
{
  __shared__ float As[KS][TS + 1];
  __shared__ float Ws[KS][TS + 1];
  const int tid = threadIdx.x;
  const int bm = blockIdx.x * TS;
  const int bn = blockIdx.y * TS;
  const int r  = tid >> 2;
  const int kc = (tid & 3) << 2;
  const int tm = (tid >> 4) << 2;
  const int tn = (tid & 15) << 2;
  float acc[4][4] = {};
  for (int k0 = 0; k0 < K; k0 += KS) {
    float4 av = make_float4(0.f, 0.f, 0.f, 0.f);
    const int row = bm + r;
    if (row < M) av = *(const float4*)(A + (size_t)row * lda + k0 + kc);
    As[kc + 0][r] = av.x; As[kc + 1][r] = av.y; As[kc + 2][r] = av.z; As[kc + 3][r] = av.w;
    float4 wv = *(const float4*)(W + (size_t)(bn + r) * ldw + k0 + kc);
    Ws[kc + 0][r] = wv.x; Ws[kc + 1][r] = wv.y; Ws[kc + 2][r] = wv.z; Ws[kc + 3][r] = wv.w;
    __syncthreads();
    #pragma unroll
    for (int kk = 0; kk < KS; ++kk) {
      float a_[4], b_[4];
      #pragma unroll
      for (int i = 0; i < 4; ++i) a_[i] = As[kk][tm + i];
      #pragma unroll
      for (int j = 0; j < 4; ++j) b_[j] = Ws[kk][tn + j];
      #pragma unroll
      for (int i = 0; i < 4; ++i)
        #pragma unroll
        for (int j = 0; j < 4; ++j) acc[i][j] = fmaf(a_[i], b_[j], acc[i][j]);
    }
    __syncthreads();
  }
  #pragma unroll
  for (int i = 0; i < 4; ++i) {
    const int row = bm + tm + i;
    if (row < M)
      *(float4*)(C + (size_t)row * ldc + bn + tn) =
          make_float4(acc[i][0], acc[i][1], acc[i][2], acc[i][3]);
  }
}

// per-vocab attention scalars
__global__ __launch_bounds__(256)
void psv_kernel(const float* __restrict__ zemb, const float* __restrict__ as_,
                const float* __restrict__ ad_, float* __restrict__ psv,
                float* __restrict__ pdv, int V)
{
  int v = (int)((blockIdx.x * 256u + threadIdx.x) >> 6);
  int l = blockIdx.y;
  int lane = threadIdx.x & 63;
  if (v >= V) return;
  float4 zv = ((const float4*)(zemb + (size_t)v * HD4 + (size_t)l * HD))[lane];
  float4 a  = ((const float4*)(as_ + (size_t)l * HD))[lane];
  float4 b  = ((const float4*)(ad_ + (size_t)l * HD))[lane];
  float s = zv.x * a.x + zv.y * a.y + zv.z * a.z + zv.w * a.w;
  float d = zv.x * b.x + zv.y * b.y + zv.z * b.z + zv.w * b.w;
  #pragma unroll
  for (int o = 32; o; o >>= 1) { s += __shfl_down(s, o); d += __shfl_down(d, o); }
  if (lane == 0) { psv[(size_t)l * V + v] = s; pdv[(size_t)l * V + v] = d; }
}

__global__ void cnt_kernel(const int* __restrict__ n2g, float* __restrict__ cnt, int N) {
  int n = blockIdx.x * 256 + threadIdx.x;
  if (n < N) unsafeAtomicAdd(&cnt[n2g[n]], 1.f);
}

__global__ __launch_bounds__(256)
void seg_accum(const float* __restrict__ X, const int* __restrict__ gather,
               const int* __restrict__ n2g, float* __restrict__ acc, int N)
{
  int n = blockIdx.x;
  if (n >= N) return;
  int h = threadIdx.x;
  int row = gather ? gather[n] : n;
  unsafeAtomicAdd(&acc[(size_t)n2g[n] * HD + h], X[(size_t)row * HD + h]);
}

// meanb[i] = bf16(acc[i] / max(cnt,1)) ; i spans [2][NB][HD]
__global__ void mean_div_b16(const float* __restrict__ acc, const float* __restrict__ cnt,
                             unsigned short* __restrict__ meanb, int total) {
  int i = blockIdx.x * 256 + threadIdx.x;
  if (i < total) meanb[i] = rne_bf16(acc[i] / fmaxf(cnt[(i >> 8) & (NB - 1)], 1.f));
}

// ---------------- CSR build (by dst) ----------------
__global__ void deg_hist(const int* __restrict__ dst, int* __restrict__ deg, int E) {
  int e = blockIdx.x * 256 + threadIdx.x;
  if (e < E) atomicAdd(&deg[dst[e]], 1);
}

#define SCB 1024
__global__ void scan_bsum(const int* __restrict__ deg, int* __restrict__ bsum, int N) {
  __shared__ int sh[256];
  int base = blockIdx.x * SCB;
  int t = threadIdx.x;
  int s = 0;
  for (int i = t; i < SCB; i += 256) { int idx = base + i; s += (idx < N) ? deg[idx] : 0; }
  sh[t] = s; __syncthreads();
  for (int o = 128; o; o >>= 1) { if (t < o) sh[t] += sh[t + o]; __syncthreads(); }
  if (t == 0) bsum[blockIdx.x] = sh[0];
}
__global__ void scan_small(int* __restrict__ bsum, int nb) {
  if (threadIdx.x == 0) {
    int acc = 0;
    for (int i = 0; i < nb; ++i) { int v = bsum[i]; bsum[i] = acc; acc += v; }
  }
}
__global__ void scan_final(const int* __restrict__ deg, const int* __restrict__ bsum,
                           int* __restrict__ rowptr, int N, int E) {
  __shared__ int sh[256];
  int base = blockIdx.x * SCB;
  int t = threadIdx.x;
  int idx0 = base + t * 4;
  int v[4]; int s = 0;
  #pragma unroll
  for (int j = 0; j < 4; ++j) { int idx = idx0 + j; v[j] = (idx < N) ? deg[idx] : 0; s += v[j]; }
  sh[t] = s; __syncthreads();
  for (int o = 1; o < 256; o <<= 1) {
    int x = (t >= o) ? sh[t - o] : 0;
    __syncthreads();
    sh[t] += x;
    __syncthreads();
  }
  int off = bsum[blockIdx.x] + ((t == 0) ? 0 : sh[t - 1]);
  #pragma unroll
  for (int j = 0; j < 4; ++j) {
    int idx = idx0 + j;
    if (idx < N) rowptr[idx] = off;
    off += v[j];
  }
  if (idx0 <= N - 1 && N - 1 < idx0 + 4) rowptr[N] = E;
}
__global__ void scatter_edges(const int* __restrict__ src, const int* __restrict__ dst,
                              const int* __restrict__ wid, int* __restrict__ cursor,
                              int* __restrict__ swids, int* __restrict__ dwids, int E) {
  int e = blockIdx.x * 256 + threadIdx.x;
  if (e >= E) return;
  int pos = atomicAdd(&cursor[dst[e]], 1);
  swids[pos] = wid[src[e]];
  dwids[pos] = wid[dst[e]];
}

// per-edge scores for all 4 layers (tables are L1-resident: 4*531*4B each)
__global__ void edge_score(const int* __restrict__ swids, const int* __restrict__ dwids,
                           const float* __restrict__ psv, const float* __restrict__ pdv,
                           float4* __restrict__ es4, int E, int V) {
  int i = blockIdx.x * 256 + threadIdx.x;
  if (i >= E) return;
  int sw = swids[i], dw = dwids[i];
  float4 e;
  e.x = lrelu(psv[0 * V + sw] + pdv[0 * V + dw]);
  e.y = lrelu(psv[1 * V + sw] + pdv[1 * V + dw]);
  e.z = lrelu(psv[2 * V + sw] + pdv[2 * V + dw]);
  e.w = lrelu(psv[3 * V + sw] + pdv[3 * V + dw]);
  es4[i] = e;
}

// ---------------- fused GAT, all 4 layers in one pass: softmax + agg + relu + BN partials
__global__ __launch_bounds__(256)
void gat_node4(const int* __restrict__ rowptr, const int* __restrict__ swids,
               const float4* __restrict__ es4, const float* __restrict__ zemb,
               unsigned short* __restrict__ hb,
               float* __restrict__ bs, float* __restrict__ bq, int N)
{
  const int lane = threadIdx.x & 63;
  const int wv   = threadIdx.x >> 6;
  const int gw   = blockIdx.x * 4 + wv;
  const int nw   = gridDim.x * 4;
  float sreg[4][4] = {}, qreg[4][4] = {};
  for (int n = gw; n < N; n += nw) {
    const int b0 = rowptr[n], b1 = rowptr[n + 1];
    float4 m = make_float4(-INFINITY, -INFINITY, -INFINITY, -INFINITY);
    for (int i = b0; i < b1; ++i) {
      float4 e = es4[i];
      m.x = fmaxf(m.x, e.x); m.y = fmaxf(m.y, e.y);
      m.z = fmaxf(m.z, e.z); m.w = fmaxf(m.w, e.w);
    }
    if (b0 == b1) m = make_float4(0.f, 0.f, 0.f, 0.f);
    float4 s = make_float4(0.f, 0.f, 0.f, 0.f);
    float4 acc[4] = {};
    for (int i = b0; i < b1; ++i) {
      float4 e = es4[i];
      float ex0 = expf(e.x - m.x), ex1 = expf(e.y - m.y);
      float ex2 = expf(e.z - m.z), ex3 = expf(e.w - m.w);
      s.x += ex0; s.y += ex1; s.z += ex2; s.w += ex3;
      const float* zb = zemb + (size_t)swids[i] * HD4 + lane * 4;
      float4 z0 = *(const float4*)(zb);
      float4 z1 = *(const float4*)(zb + HD);
      float4 z2 = *(const float4*)(zb + 2 * HD);
      float4 z3 = *(const float4*)(zb + 3 * HD);
      acc[0].x = fmaf(ex0, z0.x, acc[0].x); acc[0].y = fmaf(ex0, z0.y, acc[0].y);
      acc[0].z = fmaf(ex0, z0.z, acc[0].z); acc[0].w = fmaf(ex0, z0.w, acc[0].w);
      acc[1].x = fmaf(ex1, z1.x, acc[1].x); acc[1].y = fmaf(ex1, z1.y, acc[1].y);
      acc[1].z = fmaf(ex1, z1.z, acc[1].z); acc[1].w = fmaf(ex1, z1.w, acc[1].w);
      acc[2].x = fmaf(ex2, z2.x, acc[2].x); acc[2].y = fmaf(ex2, z2.y, acc[2].y);
      acc[2].z = fmaf(ex2, z2.z, acc[2].z); acc[2].w = fmaf(ex2, z2.w, acc[2].w);
      acc[3].x = fmaf(ex3, z3.x, acc[3].x); acc[3].y = fmaf(ex3, z3.y, acc[3].y);
      acc[3].z = fmaf(ex3, z3.z, acc[3].z); acc[3].w = fmaf(ex3, z3.w, acc[3].w);
    }
    const float i0 = 1.f / (s.x == 0.f ? 1.f : s.x);
    const float i1 = 1.f / (s.y == 0.f ? 1.f : s.y);
    const float i2 = 1.f / (s.z == 0.f ? 1.f : s.z);
    const float i3 = 1.f / (s.w == 0.f ? 1.f : s.w);
    const float invl[4] = {i0, i1, i2, i3};
    #pragma unroll
    for (int l = 0; l < 4; ++l) {
      float4 v;
      v.x = fmaxf(acc[l].x * invl[l], 0.f);
      v.y = fmaxf(acc[l].y * invl[l], 0.f);
      v.z = fmaxf(acc[l].z * invl[l], 0.f);
      v.w = fmaxf(acc[l].w * invl[l], 0.f);
      ushort4 o;
      o.x = rne_bf16(v.x); o.y = rne_bf16(v.y); o.z = rne_bf16(v.z); o.w = rne_bf16(v.w);
      ((ushort4*)(hb + (size_t)n * HD4 + l * HD))[lane] = o;
      sreg[l][0] += v.x; sreg[l][1] += v.y; sreg[l][2] += v.z; sreg[l][3] += v.w;
      qreg[l][0] = fmaf(v.x, v.x, qreg[l][0]); qreg[l][1] = fmaf(v.y, v.y, qreg[l][1]);
      qreg[l][2] = fmaf(v.z, v.z, qreg[l][2]); qreg[l][3] = fmaf(v.w, v.w, qreg[l][3]);
    }
  }
  __shared__ float ls[4][64][4];
  __shared__ float lq[4][64][4];
  for (int l = 0; l < 4; ++l) {
    #pragma unroll
    for (int j = 0; j < 4; ++j) { ls[wv][lane][j] = sreg[l][j]; lq[wv][lane][j] = qreg[l][j]; }
    __syncthreads();
    if (wv == 0) {
      #pragma unroll
      for (int j = 0; j < 4; ++j) {
        float s4 = ls[0][lane][j] + ls[1][lane][j] + ls[2][lane][j] + ls[3][lane][j];
        float q4 = lq[0][lane][j] + lq[1][lane][j] + lq[2][lane][j] + lq[3][lane][j];
        unsafeAtomicAdd(&bs[l * HD + lane * 4 + j], s4);
        unsafeAtomicAdd(&bq[l * HD + lane * 4 + j], q4);
      }
    }
    __syncthreads();
  }
}

// all 4 layers' BN coefficients in one launch (gamma/beta are [4,256] contiguous)
__global__ void bn_fin4(const float* __restrict__ bs, const float* __restrict__ bq,
                        const float* __restrict__ gamma, const float* __restrict__ beta,
                        float* __restrict__ sc, float* __restrict__ sh, float invN)
{
  int h = blockIdx.x * 256 + threadIdx.x;
  float mu  = bs[h] * invN;
  float var = fmaxf(bq[h] * invN - mu * mu, 0.f);
  float s = gamma[h] * rsqrtf(var + 1e-5f);
  sc[h] = s;
  sh[h] = fmaf(-mu, s, beta[h]);
}

// torch GRU cell; gh==null means hprev==0; optional bf16 mirror write
__global__ __launch_bounds__(256)
void gru_cell(const float* __restrict__ gi, int gild,
              const float* __restrict__ gh,
              const float* __restrict__ bih, const float* __restrict__ bhh,
              const float* __restrict__ hprev, int hld,
              float* __restrict__ out, int outld,
              unsigned short* __restrict__ outb, int Bn)
{
  int i = blockIdx.x * 256 + threadIdx.x;
  if (i >= Bn * HD) return;
  int b = i >> 8, h = i & 255;
  const float* gr = gi + (size_t)b * gild;
  float ir  = gr[h]       + bih[h];
  float iz  = gr[HD + h]  + bih[HD + h];
  float in_ = gr[HD2 + h] + bih[HD2 + h];
  float hrv = bhh[h], hzv = bhh[HD + h], hnv = bhh[HD2 + h];
  if (gh) {
    const float* gg = gh + (size_t)b * HD3;
    hrv += gg[h]; hzv += gg[HD + h]; hnv += gg[HD2 + h];
  }
  float hp = hprev ? hprev[(size_t)b * hld + h] : 0.f;
  float rg = 1.f / (1.f + expf(-(ir + hrv)));
  float zg = 1.f / (1.f + expf(-(iz + hzv)));
  float n  = tanhf(fmaf(rg, hnv, in_));
  float hv = (1.f - zg) * n + zg * hp;
  out[(size_t)b * outld + h] = hv;
  if (outb) outb[(size_t)b * outld + h] = rne_bf16(hv);
}

__global__ void readout_k(const float* __restrict__ y0, const float* __restrict__ hf1,
                          const float* __restrict__ hf2, float* __restrict__ out, int Bn)
{
  int i = blockIdx.x * 256 + threadIdx.x;
  if (i >= Bn * HD) return;
  int b = i >> 8, h = i & 255;
  out[i] = y0[(size_t)b * HD4 + HD2 + h] + y0[(size_t)b * HD4 + HD + h] + hf1[i] + hf2[i];
}

extern "C" void kernel_launch(void* const* d_in, const int* in_sizes, int n_in,
                              void* d_out, int out_size, void* d_ws, size_t ws_size,
                              hipStream_t stream)
{
  const int*   wid   = (const int*)d_in[0];
  const int*   src   = (const int*)d_in[1];
  const int*   dst   = (const int*)d_in[2];
  const int*   n2g   = (const int*)d_in[3];
  const float* emb   = (const float*)d_in[4];
  const float* gatW  = (const float*)d_in[5];
  const float* gatAs = (const float*)d_in[6];
  const float* gatAd = (const float*)d_in[7];
  const float* gatG  = (const float*)d_in[8];
  const float* gatB  = (const float*)d_in[9];
  const float* Wout  = (const float*)d_in[10];
  const float* bout  = (const float*)d_in[11];
  const float* Wih0  = (const float*)d_in[12];
  const float* Whh0  = (const float*)d_in[13];
  const float* bih0  = (const float*)d_in[14];
  const float* bhh0  = (const float*)d_in[15];
  const float* Wih1  = (const float*)d_in[16];
  const float* Whh1  = (const float*)d_in[17];
  const float* bih1  = (const float*)d_in[18];
  const float* bhh1  = (const float*)d_in[19];
  (void)n_in; (void)out_size;

  const int N = in_sizes[0];
  const int E = in_sizes[1];
  const int V = in_sizes[4] / HD;

  float* out_newh = (float*)d_out;
  float* out_read = out_newh + (size_t)N * HD;

  // ---- workspace carve-up (256B-aligned); habf LAST
  char* cp  = (char*)d_ws;
  auto alloc = [&](size_t bytes) { char* r = cp; cp += (bytes + 255) & ~(size_t)255; return r; };
  float* zemb  = (float*)alloc((size_t)V * HD4 * 4);
  float* psv   = (float*)alloc(4 * (size_t)V * 4);
  float* pdv   = (float*)alloc(4 * (size_t)V * 4);
  float* cnt   = (float*)alloc(((size_t)NB + 2 * (size_t)NB * HD) * 4);  // cnt|msum1|msum2
  float* msum  = cnt + NB;
  unsigned short* meanb = (unsigned short*)alloc((size_t)2 * NB * HD * 2);  // [2][B][H] bf16
  float* gi0   = (float*)alloc((size_t)2 * NB * 1536 * 4);  // [2*B,1536] input gates (L0/L1 reuse)
  float* gh    = (float*)alloc((size_t)NB * HD3 * 4);
  float* y0    = (float*)alloc((size_t)NB * HD4 * 4);
  unsigned short* y0b = (unsigned short*)alloc((size_t)NB * HD4 * 2);
  float* htA   = (float*)alloc((size_t)NB * HD * 4);
  unsigned short* htAb = (unsigned short*)alloc((size_t)NB * HD * 2);
  float* hf1   = (float*)alloc((size_t)NB * HD * 4);
  float* hf2   = (float*)alloc((size_t)NB * HD * 4);
  float* bnsum = (float*)alloc(2048 * 4);            // bnsum[1024]|bnsq[1024]
  float* bnsq  = bnsum + 1024;
  float* bnsc  = (float*)alloc(1024 * 4);
  float* bnsh  = (float*)alloc(1024 * 4);
  unsigned short* Wp = (unsigned short*)alloc((size_t)HD * HD4 * 2);
  float* shiftv = (float*)alloc(HD * 4);
  unsigned short* Wih0b16 = (unsigned short*)alloc((size_t)2 * HD3 * HD * 2);
  unsigned short* Whh0b16 = (unsigned short*)alloc((size_t)2 * HD3 * HD * 2);
  unsigned short* Wih1b16 = (unsigned short*)alloc((size_t)2 * HD3 * HD2 * 2);
  unsigned short* Whh1b16 = (unsigned short*)alloc((size_t)2 * HD3 * HD * 2);
  int* deg     = (int*)alloc((size_t)N * 4);
  int* rowptr  = (int*)alloc((size_t)(N + 4) * 4);
  int* cursor  = (int*)alloc((size_t)N * 4);
  int* swids   = (int*)alloc((size_t)E * 4);
  int* dwids   = (int*)alloc((size_t)E * 4);
  float4* es4  = (float4*)alloc((size_t)E * 16);
  int* bsum    = (int*)alloc(256 * 4);
  unsigned short* habf = (unsigned short*)alloc((size_t)N * HD4 * 2);

  auto gemmb = [&](const unsigned short* A, int lda, const unsigned short* B, int ldb,
                   const float* sv, float* C, int ldc, int M, int Nout, int K, int accum) {
    gemm_mfma<<<dim3((unsigned)((M + 127) / 128), (unsigned)(Nout / 128)), 256, 0, stream>>>(
        A, lda, B, ldb, sv, C, ldc, M, K, accum);
  };
  auto cell = [&](const float* gi_, int gild, const float* gh_, const float* bi, const float* bh,
                  const float* hp, int hld, float* op, int ol, unsigned short* ob) {
    gru_cell<<<(NB * HD + 255) / 256, 256, 0, stream>>>(gi_, gild, gh_, bi, bh, hp, hld, op, ol, ob, NB);
  };

  // ---- CSR by destination
  const int nsb = (N + SCB - 1) / SCB;
  hipMemsetAsync(deg, 0, (size_t)N * sizeof(int), stream);
  deg_hist<<<(E + 255) / 256, 256, 0, stream>>>(dst, deg, E);
  scan_bsum<<<nsb, 256, 0, stream>>>(deg, bsum, N);
  scan_small<<<1, 64, 0, stream>>>(bsum, nsb);
  scan_final<<<nsb, 256, 0, stream>>>(deg, bsum, rowptr, N, E);
  hipMemcpyAsync(cursor, rowptr, (size_t)N * sizeof(int), hipMemcpyDeviceToDevice, stream);
  scatter_edges<<<(E + 255) / 256, 256, 0, stream>>>(src, dst, wid, cursor, swids, dwids, E);

  // zemb = emb @ [4 layers W]^T ; per-vocab attention scalars; per-edge scores
  {
    dim3 g((unsigned)((V + TS - 1) / TS), (unsigned)(HD4 / TS));
    gemm_tn<<<g, 256, 0, stream>>>(emb, HD, gatW, HD, zemb, HD4, V, HD);
  }
  psv_kernel<<<dim3((V + 3) / 4, 4), 256, 0, stream>>>(zemb, gatAs, gatAd, psv, pdv, V);
  edge_score<<<(E + 255) / 256, 256, 0, stream>>>(swids, dwids, psv, pdv, es4, E, V);

  // GRU weights -> bf16 (once per call)
  f2b_kernel<<<(2 * HD3 * HD + 255) / 256, 256, 0, stream>>>(Wih0, Wih0b16, 2 * HD3 * HD);
  f2b_kernel<<<(2 * HD3 * HD + 255) / 256, 256, 0, stream>>>(Whh0, Whh0b16, 2 * HD3 * HD);
  f2b_kernel<<<(2 * HD3 * HD2 + 255) / 256, 256, 0, stream>>>(Wih1, Wih1b16, 2 * HD3 * HD2);
  f2b_kernel<<<(2 * HD3 * HD + 255) / 256, 256, 0, stream>>>(Whh1, Whh1b16, 2 * HD3 * HD);

  // graph means: msum1 = seg_sum(emb[wid]) ; (msum2 later)
  hipMemsetAsync(cnt, 0, (size_t)(NB + 2 * NB * HD) * sizeof(float), stream);
  cnt_kernel<<<(N + 255) / 256, 256, 0, stream>>>(n2g, cnt, N);
  seg_accum<<<N, 256, 0, stream>>>(emb, wid, n2g, msum, N);

  // ---- fused GAT (4 layers) + BN + folded MFMA projection
  hipMemsetAsync(bnsum, 0, 2048 * sizeof(float), stream);
  gat_node4<<<2048, 256, 0, stream>>>(rowptr, swids, es4, zemb, habf, bnsum, bnsq, N);
  bn_fin4<<<4, 256, 0, stream>>>(bnsum, bnsq, gatG, gatB, bnsc, bnsh, 1.f / (float)N);
  fold_w<<<HD, 256, 0, stream>>>(Wout, HD4, bnsc, bnsh, bout, Wp, HD4, shiftv, HD4);
  gemmb(habf, HD4, Wp, HD4, shiftv, out_newh, HD, N, HD, HD4, 0);

  // mean2 = seg_mean(new_h);  means -> bf16 stacked [2][B][H]
  seg_accum<<<N, 256, 0, stream>>>(out_newh, nullptr, n2g, msum + (size_t)NB * HD, N);
  mean_div_b16<<<(2 * NB * HD + 255) / 256, 256, 0, stream>>>(msum, cnt, meanb, 2 * NB * HD);

  // ---- GRU (T=2, 2 layers, bidir) on MFMA. y0[b,c]: c = t*2H + dir*H + h
  // layer0 input gates, both t and both dirs in one GEMM: [2B,1536] = meanb @ Wih0^T
  gemmb(meanb, HD, Wih0b16, HD, nullptr, gi0, 1536, 2 * NB, 1536, HD, 0);
  // L0 fwd t0
  cell(gi0, 1536, nullptr, bih0, bhh0, nullptr, 0, y0 + 0, HD4, y0b);
  // L0 fwd t1
  gemmb(y0b + 0, HD4, Whh0b16, HD, nullptr, gh, HD3, NB, HD3, HD, 0);
  cell(gi0 + (size_t)NB * 1536, 1536, gh, bih0, bhh0, y0 + 0, HD4, y0 + HD2, HD4, y0b + HD2);
  // L0 bwd t1 (first step of reverse)
  cell(gi0 + (size_t)NB * 1536 + HD3, 1536, nullptr, bih0 + HD3, bhh0 + HD3, nullptr, 0,
       y0 + HD2 + HD, HD4, y0b + HD2 + HD);
  // L0 bwd t0
  gemmb(y0b + HD2 + HD, HD4, Whh0b16 + (size_t)HD3 * HD, HD, nullptr, gh, HD3, NB, HD3, HD, 0);
  cell(gi0 + HD3, 1536, gh, bih0 + HD3, bhh0 + HD3, y0 + HD2 + HD, HD4, y0 + HD, HD4, y0b + HD);
  // layer1 input gates: view y0b as [2B,512] (row = b*2+t): [2B,1536] = y0b @ Wih1^T
  gemmb(y0b, HD2, Wih1b16, HD2, nullptr, gi0, 1536, 2 * NB, 1536, HD2, 0);
  // L1 fwd t0 (row stride for fixed t is 2*1536 = 3072)
  cell(gi0, 3072, nullptr, bih1, bhh1, nullptr, 0, htA, HD, htAb);
  // L1 fwd t1 -> hf1 (= h_last fwd)
  gemmb(htAb, HD, Whh1b16, HD, nullptr, gh, HD3, NB, HD3, HD, 0);
  cell(gi0 + 1536, 3072, gh, bih1, bhh1, htA, HD, hf1, HD, nullptr);
  // L1 bwd t1
  cell(gi0 + 1536 + HD3, 3072, nullptr, bih1 + HD3, bhh1 + HD3, nullptr, 0, htA, HD, htAb);
  // L1 bwd t0 -> hf2 (= h_last bwd)
  gemmb(htAb, HD, Whh1b16 + (size_t)HD3 * HD, HD, nullptr, gh, HD3, NB, HD3, HD, 0);
  cell(gi0 + HD3, 3072, gh, bih1 + HD3, bhh1 + HD3, htA, HD, hf2, HD, nullptr);

  readout_k<<<(NB * HD + 255) / 256, 256, 0, stream>>>(y0, hf1, hf2, out_read, NB);
}